// Round 3
// baseline (389.403 us; speedup 1.0000x reference)
//
#include <hip/hip_runtime.h>
#include <hip/hip_bf16.h>

typedef __attribute__((ext_vector_type(8))) short short8;
typedef __attribute__((ext_vector_type(4))) float f32x4;

#define SEQ 2048
#define DIM 3072
#define NHEAD 24
#define HDIM 128

__device__ __forceinline__ unsigned short f2bf(float f) {
  unsigned int b = __float_as_uint(f);
  b += 0x7fffu + ((b >> 16) & 1u);
  return (unsigned short)(b >> 16);
}
__device__ __forceinline__ float bf2f(unsigned short u) {
  return __uint_as_float(((unsigned int)u) << 16);
}

__device__ __forceinline__ void async16(const void* g, void* l) {
  __builtin_amdgcn_global_load_lds(
      (const __attribute__((address_space(1))) unsigned int*)g,
      (__attribute__((address_space(3))) unsigned int*)l, 16, 0, 0);
}

// ---------------- cast x (fp32 -> bf16), 8 elems/thread ----------------
__global__ void k_cvt_x(const float* __restrict__ x, unsigned short* __restrict__ xb) {
  int idx = (blockIdx.x * 256 + threadIdx.x) * 8;
  float4 a = *(const float4*)(x + idx);
  float4 b = *(const float4*)(x + idx + 4);
  short8 o;
  o[0] = (short)f2bf(a.x); o[1] = (short)f2bf(a.y);
  o[2] = (short)f2bf(a.z); o[3] = (short)f2bf(a.w);
  o[4] = (short)f2bf(b.x); o[5] = (short)f2bf(b.y);
  o[6] = (short)f2bf(b.z); o[7] = (short)f2bf(b.w);
  *(short8*)(xb + idx) = o;
}

// ---------------- transpose + cast W (K x N fp32) -> Wt (N x K bf16), 64x64 tiles ----------------
__global__ __launch_bounds__(256) void k_transpose(const float* __restrict__ w,
                                                   unsigned short* __restrict__ wt) {
  __shared__ unsigned short tile[64][68];  // 136 B rows (8-aligned)
  int t = threadIdx.x;
  int c4 = (t & 15) * 4;
  int r0 = t >> 4;  // 0..15
  int n0 = blockIdx.x * 64, k0 = blockIdx.y * 64;
#pragma unroll
  for (int j = 0; j < 4; ++j) {
    int r = r0 + 16 * j;  // k-local
    float4 v = *(const float4*)(w + (size_t)(k0 + r) * DIM + n0 + c4);
    ushort4 u;
    u.x = f2bf(v.x); u.y = f2bf(v.y); u.z = f2bf(v.z); u.w = f2bf(v.w);
    *(ushort4*)&tile[r][c4] = u;
  }
  __syncthreads();
#pragma unroll
  for (int j = 0; j < 4; ++j) {
    int nn = r0 + 16 * j;  // n-local
    ushort4 u;
    u.x = tile[c4 + 0][nn]; u.y = tile[c4 + 1][nn];
    u.z = tile[c4 + 2][nn]; u.w = tile[c4 + 3][nn];
    *(ushort4*)(wt + (size_t)(n0 + nn) * DIM + k0 + c4) = u;
  }
}

// ---------------- transpose V (bf16): vb[s][h*128+d] -> vt[h][d][s] ----------------
__global__ void k_transpose_v(const unsigned short* __restrict__ v,
                              unsigned short* __restrict__ vt) {
  __shared__ unsigned short tile[32][33];
  int tx = threadIdx.x & 31, ty = threadIdx.x >> 5;  // 0..7
  int s0 = blockIdx.x * 32, d0 = blockIdx.y * 32, h = blockIdx.z;
#pragma unroll
  for (int i = 0; i < 4; ++i) {
    int r = ty + i * 8;
    tile[r][tx] = v[(size_t)(s0 + r) * DIM + h * HDIM + d0 + tx];
  }
  __syncthreads();
#pragma unroll
  for (int i = 0; i < 4; ++i) {
    int r = ty + i * 8;
    vt[(size_t)(h * HDIM + d0 + r) * SEQ + s0 + tx] = tile[tx][r];
  }
}

// ---------------- GEMM: C(2048 x 3072) = xb @ Wt^T + bias, bf16 out ----------------
// 128x128 tile, BK=64, 4 waves (2x2). T2 XOR-swizzled LDS (pre-swizzled source),
// XCD-bijective grid swizzle (384 = 8 * 48, B-panels clustered per XCD).
__global__ __launch_bounds__(256) void k_gemm(const unsigned short* __restrict__ xb,
                                              const unsigned short* __restrict__ wt,
                                              const float* __restrict__ bias,
                                              unsigned short* __restrict__ out) {
  __shared__ unsigned short As[128 * 64];
  __shared__ unsigned short Bs[128 * 64];
  int t = threadIdx.x;
  int w = t >> 6, l = t & 63;
  int wr = w >> 1, wc = w & 1;
  int lr = l & 15, kc = l >> 4;
  int fid = blockIdx.x;
  int logical = (fid & 7) * 48 + (fid >> 3);  // bijective: 384 = 8*48
  int bm = logical & 15, bn = logical >> 4;

  f32x4 acc[4][4];
#pragma unroll
  for (int m = 0; m < 4; ++m)
#pragma unroll
    for (int n = 0; n < 4; ++n) acc[m][n] = (f32x4){0.f, 0.f, 0.f, 0.f};

  const char* aB = (const char*)xb;
  const char* bB = (const char*)wt;
  char* asmB = (char*)As;
  char* bsmB = (char*)Bs;
  int sw = (lr & 7) << 4;

  for (int k0 = 0; k0 < DIM; k0 += 64) {
#pragma unroll
    for (int i = 0; i < 4; ++i) {
      int off = (t + 256 * i) * 16;
      int row = off >> 7;  // 128 B per row (64 bf16)
      int cb = off & 127;
      int scb = cb ^ ((row & 7) << 4);
      async16(aB + ((size_t)(bm * 128 + row) * DIM + k0) * 2 + scb, asmB + off);
      async16(bB + ((size_t)(bn * 128 + row) * DIM + k0) * 2 + scb, bsmB + off);
    }
    __syncthreads();
#pragma unroll
    for (int kk = 0; kk < 2; ++kk) {
      short8 af[4], bf[4];
#pragma unroll
      for (int m = 0; m < 4; ++m)
        af[m] = *(const short8*)(asmB + (wr * 64 + m * 16 + lr) * 128 +
                                 ((kk * 64 + kc * 16) ^ sw));
#pragma unroll
      for (int n = 0; n < 4; ++n)
        bf[n] = *(const short8*)(bsmB + (wc * 64 + n * 16 + lr) * 128 +
                                 ((kk * 64 + kc * 16) ^ sw));
#pragma unroll
      for (int m = 0; m < 4; ++m)
#pragma unroll
        for (int n = 0; n < 4; ++n)
          acc[m][n] = __builtin_amdgcn_mfma_f32_16x16x32_bf16(af[m], bf[n], acc[m][n], 0, 0, 0);
    }
    __syncthreads();
  }

  int lq = l >> 4;
#pragma unroll
  for (int m = 0; m < 4; ++m)
#pragma unroll
    for (int n = 0; n < 4; ++n) {
      int gcol = bn * 128 + wc * 64 + n * 16 + lr;
      float bv = bias[gcol];
#pragma unroll
      for (int i = 0; i < 4; ++i) {
        int grow = bm * 128 + wr * 64 + m * 16 + lq * 4 + i;
        out[(size_t)grow * DIM + gcol] = f2bf(acc[m][n][i] + bv);
      }
    }
}

// ---------------- RMSNorm + RoPE, in-place on bf16 ----------------
__global__ void k_normrope(unsigned short* __restrict__ qk, const float* __restrict__ cosb,
                           const float* __restrict__ sinb, const float* __restrict__ g,
                           float scale) {
  int t = threadIdx.x;
  int w = t >> 6, l = t & 63;
  int row = blockIdx.x * 4 + w;
  int s_idx = row / NHEAD, head = row % NHEAD;
  size_t base = (size_t)s_idx * DIM + head * HDIM;
  unsigned int pair = *(const unsigned int*)(qk + base + 2 * l);
  float x0 = bf2f((unsigned short)(pair & 0xffffu));
  float x1 = bf2f((unsigned short)(pair >> 16));
  float ss = x0 * x0 + x1 * x1;
#pragma unroll
  for (int off = 1; off < 64; off <<= 1) ss += __shfl_xor(ss, off);
  float r = rsqrtf(ss * (1.0f / 128.0f) + 1e-6f);
  float g0 = g[2 * l], g1 = g[2 * l + 1];
  float c0 = cosb[s_idx * HDIM + 2 * l], c1 = cosb[s_idx * HDIM + 2 * l + 1];
  float s0 = sinb[s_idx * HDIM + 2 * l], s1 = sinb[s_idx * HDIM + 2 * l + 1];
  float xn0 = x0 * r * g0, xn1 = x1 * r * g1;
  float o0 = (xn0 * c0 - xn1 * s0) * scale;
  float o1 = (xn1 * c1 + xn0 * s1) * scale;
  unsigned int po = (unsigned int)f2bf(o0) | ((unsigned int)f2bf(o1) << 16);
  *(unsigned int*)(qk + base + 2 * l) = po;
}

// ---------------- Flash attention, 2-phase K/V double-buffer ----------------
// q pre-scaled by (1/sqrt(128))*log2(e): softmax in exp2 domain.
__global__ __launch_bounds__(256) void k_attn(const unsigned short* __restrict__ q,
                                              const unsigned short* __restrict__ k,
                                              const unsigned short* __restrict__ vt,
                                              float* __restrict__ out) {
  __shared__ unsigned short Ksm[2][64 * 128];   // [kv][d], swizzled
  __shared__ unsigned short Vtsm[2][128 * 64];  // [d][kv], swizzled
  __shared__ unsigned short Psm[4][16 * 72];    // per-wave P
  int t = threadIdx.x;
  int w = t >> 6, l = t & 63;
  int lr = l & 15, lq = l >> 4;
  int fid = blockIdx.x;
  int logical = (fid & 7) * 96 + (fid >> 3);  // bijective: 768 = 8*96
  int qt = logical & 31, h = logical >> 5;
  int q0 = qt * 64 + w * 16;

  const char* kbase = (const char*)k + (size_t)h * HDIM * 2;
  const char* vbase = (const char*)vt + (size_t)h * HDIM * SEQ * 2;

  short8 qf[4];
  {
    size_t qrow = (size_t)(q0 + lr) * DIM + h * HDIM;
#pragma unroll
    for (int kc = 0; kc < 4; ++kc) qf[kc] = *(const short8*)(q + qrow + kc * 32 + lq * 8);
  }

  f32x4 o[8];
#pragma unroll
  for (int dc = 0; dc < 8; ++dc) o[dc] = (f32x4){0.f, 0.f, 0.f, 0.f};
  float m_[4] = {-1e30f, -1e30f, -1e30f, -1e30f};
  float lsum[4] = {0.f, 0.f, 0.f, 0.f};

  auto stageK = [&](int kt, int buf) {
#pragma unroll
    for (int i = 0; i < 4; ++i) {
      int off = (t + 256 * i) * 16;
      int row = off >> 8;
      int cb = off & 255;
      int scb = cb ^ ((row & 7) << 4);
      async16(kbase + ((size_t)(kt * 64 + row) * DIM) * 2 + scb, (char*)Ksm[buf] + off);
    }
  };
  auto stageV = [&](int kt, int buf) {
#pragma unroll
    for (int i = 0; i < 4; ++i) {
      int off = (t + 256 * i) * 16;
      int row = off >> 7;
      int cb = off & 127;
      int scb = cb ^ ((row & 7) << 4);
      async16(vbase + ((size_t)row * SEQ + kt * 64) * 2 + scb, (char*)Vtsm[buf] + off);
    }
  };

  stageK(0, 0);
  stageV(0, 0);
  __syncthreads();

  for (int kt = 0; kt < 32; ++kt) {
    int cur = kt & 1;
    if (kt < 31) {
      stageK(kt + 1, cur ^ 1);
      stageV(kt + 1, cur ^ 1);
    }

    // S = Q K^T  (16 x 64 per wave)
    f32x4 s[4];
#pragma unroll
    for (int c = 0; c < 4; ++c) s[c] = (f32x4){0.f, 0.f, 0.f, 0.f};
    const char* Kc = (const char*)Ksm[cur];
    __builtin_amdgcn_s_setprio(1);
#pragma unroll
    for (int c = 0; c < 4; ++c)
#pragma unroll
      for (int kc = 0; kc < 4; ++kc) {
        short8 kf = *(const short8*)(Kc + (c * 16 + lr) * 256 +
                                     ((kc * 64 + lq * 16) ^ ((lr & 7) << 4)));
        s[c] = __builtin_amdgcn_mfma_f32_16x16x32_bf16(qf[kc], kf, s[c], 0, 0, 0);
      }
    __builtin_amdgcn_s_setprio(0);

    // online softmax in exp2 domain (row = lq*4+i, reduce across 16 lanes)
    float mt[4];
#pragma unroll
    for (int i = 0; i < 4; ++i) {
      float mm = fmaxf(fmaxf(s[0][i], s[1][i]), fmaxf(s[2][i], s[3][i]));
#pragma unroll
      for (int off = 1; off < 16; off <<= 1) mm = fmaxf(mm, __shfl_xor(mm, off));
      mt[i] = mm;
    }
    bool ok = (mt[0] <= m_[0] + 10.0f) && (mt[1] <= m_[1] + 10.0f) &&
              (mt[2] <= m_[2] + 10.0f) && (mt[3] <= m_[3] + 10.0f);
    if (!__all(ok)) {
#pragma unroll
      for (int i = 0; i < 4; ++i) {
        float mn = fmaxf(m_[i], mt[i]);
        float corr = exp2f(m_[i] - mn);
        m_[i] = mn;
        lsum[i] *= corr;
#pragma unroll
        for (int dc = 0; dc < 8; ++dc) o[dc][i] *= corr;
      }
    }
#pragma unroll
    for (int c = 0; c < 4; ++c)
#pragma unroll
      for (int i = 0; i < 4; ++i) s[c][i] = exp2f(s[c][i] - m_[i]);
#pragma unroll
    for (int i = 0; i < 4; ++i) {
      float rs = s[0][i] + s[1][i] + s[2][i] + s[3][i];
#pragma unroll
      for (int off = 1; off < 16; off <<= 1) rs += __shfl_xor(rs, off);
      lsum[i] += rs;
    }

    // P -> per-wave LDS via packed bf16 converts
    unsigned short* pw = Psm[w];
#pragma unroll
    for (int c = 0; c < 4; ++c) {
      __hip_bfloat162 p01 = __float22bfloat162_rn(make_float2(s[c][0], s[c][1]));
      __hip_bfloat162 p23 = __float22bfloat162_rn(make_float2(s[c][2], s[c][3]));
      unsigned int u01 = *(unsigned int*)&p01;
      unsigned int u23 = *(unsigned int*)&p23;
      pw[(lq * 4 + 0) * 72 + c * 16 + lr] = (unsigned short)(u01 & 0xffffu);
      pw[(lq * 4 + 1) * 72 + c * 16 + lr] = (unsigned short)(u01 >> 16);
      pw[(lq * 4 + 2) * 72 + c * 16 + lr] = (unsigned short)(u23 & 0xffffu);
      pw[(lq * 4 + 3) * 72 + c * 16 + lr] = (unsigned short)(u23 >> 16);
    }
    short8 pf[2];
#pragma unroll
    for (int kvc = 0; kvc < 2; ++kvc)
      pf[kvc] = *(const short8*)(pw + lr * 72 + kvc * 32 + lq * 8);

    // O += P V
    const char* Vc = (const char*)Vtsm[cur];
    __builtin_amdgcn_s_setprio(1);
#pragma unroll
    for (int dc = 0; dc < 8; ++dc)
#pragma unroll
      for (int kvc = 0; kvc < 2; ++kvc) {
        short8 vf = *(const short8*)(Vc + (dc * 16 + lr) * 128 +
                                     ((kvc * 64 + lq * 16) ^ ((lr & 7) << 4)));
        o[dc] = __builtin_amdgcn_mfma_f32_16x16x32_bf16(pf[kvc], vf, o[dc], 0, 0, 0);
      }
    __builtin_amdgcn_s_setprio(0);

    __syncthreads();
  }

#pragma unroll
  for (int dc = 0; dc < 8; ++dc)
#pragma unroll
    for (int i = 0; i < 4; ++i) {
      int grow = q0 + lq * 4 + i;
      out[(size_t)grow * DIM + h * HDIM + dc * 16 + lr] = o[dc][i] / lsum[i];
    }
}

extern "C" void kernel_launch(void* const* d_in, const int* in_sizes, int n_in,
                              void* d_out, int out_size, void* d_ws, size_t ws_size,
                              hipStream_t stream) {
  const float* x = (const float*)d_in[0];
  const float* rope_cos = (const float*)d_in[1];
  const float* rope_sin = (const float*)d_in[2];
  const float* Wq = (const float*)d_in[3];
  const float* bq = (const float*)d_in[4];
  const float* Wk = (const float*)d_in[5];
  const float* bk = (const float*)d_in[6];
  const float* Wv = (const float*)d_in[7];
  const float* bv = (const float*)d_in[8];
  const float* gq = (const float*)d_in[9];
  const float* gk = (const float*)d_in[10];
  float* out = (float*)d_out;

  unsigned short* xb = (unsigned short*)d_ws;               // 2048*3072
  unsigned short* wt = xb + (size_t)SEQ * DIM;              // 3072*3072 (reused as vt)
  unsigned short* qb = wt + (size_t)DIM * DIM;              // 2048*3072
  unsigned short* kb = qb + (size_t)SEQ * DIM;
  unsigned short* vb = kb + (size_t)SEQ * DIM;
  unsigned short* vtb = wt;  // vt: 24*128*2048 bf16 = 12.6 MB <= wt slab

  k_cvt_x<<<3072, 256, 0, stream>>>(x, xb);

  dim3 tg(DIM / 64, DIM / 64);

  k_transpose<<<tg, 256, 0, stream>>>(Wq, wt);
  k_gemm<<<384, 256, 0, stream>>>(xb, wt, bq, qb);
  k_transpose<<<tg, 256, 0, stream>>>(Wk, wt);
  k_gemm<<<384, 256, 0, stream>>>(xb, wt, bk, kb);
  k_transpose<<<tg, 256, 0, stream>>>(Wv, wt);
  k_gemm<<<384, 256, 0, stream>>>(xb, wt, bv, vb);

  // q scale = (1/sqrt(128)) * log2(e)  -> exp2-domain softmax
  k_normrope<<<SEQ * NHEAD / 4, 256, 0, stream>>>(qb, rope_cos, rope_sin, gq, 0.12751744f);
  k_normrope<<<SEQ * NHEAD / 4, 256, 0, stream>>>(kb, rope_cos, rope_sin, gk, 1.0f);

  k_transpose_v<<<dim3(SEQ / 32, HDIM / 32, NHEAD), 256, 0, stream>>>(vb, vtb);
  k_attn<<<SEQ / 64 * NHEAD, 256, 0, stream>>>(qb, kb, vtb, out);
}

// Round 4
// 351.276 us; speedup vs baseline: 1.1085x; 1.1085x over previous
//
#include <hip/hip_runtime.h>
#include <hip/hip_bf16.h>

typedef __attribute__((ext_vector_type(8))) short short8;
typedef __attribute__((ext_vector_type(4))) float f32x4;

#define SEQ 2048
#define DIM 3072
#define NHEAD 24
#define HDIM 128

__device__ __forceinline__ unsigned short f2bf(float f) {
  unsigned int b = __float_as_uint(f);
  b += 0x7fffu + ((b >> 16) & 1u);
  return (unsigned short)(b >> 16);
}
__device__ __forceinline__ float bf2f(unsigned short u) {
  return __uint_as_float(((unsigned int)u) << 16);
}

__device__ __forceinline__ void async16(const void* g, void* l) {
  __builtin_amdgcn_global_load_lds(
      (const __attribute__((address_space(1))) unsigned int*)g,
      (__attribute__((address_space(3))) unsigned int*)l, 16, 0, 0);
}

// ---------------- cast x (fp32 -> bf16), 8 elems/thread ----------------
__global__ void k_cvt_x(const float* __restrict__ x, unsigned short* __restrict__ xb) {
  int idx = (blockIdx.x * 256 + threadIdx.x) * 8;
  float4 a = *(const float4*)(x + idx);
  float4 b = *(const float4*)(x + idx + 4);
  short8 o;
  o[0] = (short)f2bf(a.x); o[1] = (short)f2bf(a.y);
  o[2] = (short)f2bf(a.z); o[3] = (short)f2bf(a.w);
  o[4] = (short)f2bf(b.x); o[5] = (short)f2bf(b.y);
  o[6] = (short)f2bf(b.z); o[7] = (short)f2bf(b.w);
  *(short8*)(xb + idx) = o;
}

// ---------------- transpose + cast W (K x N fp32) -> Wt (N x K bf16), 64x64 tiles ----------------
__global__ __launch_bounds__(256) void k_transpose(const float* __restrict__ w,
                                                   unsigned short* __restrict__ wt) {
  __shared__ unsigned short tile[64][68];
  int t = threadIdx.x;
  int c4 = (t & 15) * 4;
  int r0 = t >> 4;
  int n0 = blockIdx.x * 64, k0 = blockIdx.y * 64;
#pragma unroll
  for (int j = 0; j < 4; ++j) {
    int r = r0 + 16 * j;
    float4 v = *(const float4*)(w + (size_t)(k0 + r) * DIM + n0 + c4);
    ushort4 u;
    u.x = f2bf(v.x); u.y = f2bf(v.y); u.z = f2bf(v.z); u.w = f2bf(v.w);
    *(ushort4*)&tile[r][c4] = u;
  }
  __syncthreads();
#pragma unroll
  for (int j = 0; j < 4; ++j) {
    int nn = r0 + 16 * j;
    ushort4 u;
    u.x = tile[c4 + 0][nn]; u.y = tile[c4 + 1][nn];
    u.z = tile[c4 + 2][nn]; u.w = tile[c4 + 3][nn];
    *(ushort4*)(wt + (size_t)(n0 + nn) * DIM + k0 + c4) = u;
  }
}

// ---------------- GEMM: C(2048 x 3072) = xb @ Wt^T + bias, bf16 out ----------------
// 128x128 tile, BK=64, T2 XOR-swizzle, XCD-bijective grid swizzle.
// vmode=1: write output transposed as out[col][row] with row-stride SEQ (V path).
__global__ __launch_bounds__(256) void k_gemm(const unsigned short* __restrict__ xb,
                                              const unsigned short* __restrict__ wt,
                                              const float* __restrict__ bias,
                                              unsigned short* __restrict__ out,
                                              int vmode) {
  __shared__ unsigned short As[128 * 64];
  __shared__ unsigned short Bs[128 * 64];
  int t = threadIdx.x;
  int w = t >> 6, l = t & 63;
  int wr = w >> 1, wc = w & 1;
  int lr = l & 15, kc = l >> 4;
  int fid = blockIdx.x;
  int logical = (fid & 7) * 48 + (fid >> 3);  // bijective: 384 = 8*48
  int bm = logical & 15, bn = logical >> 4;

  f32x4 acc[4][4];
#pragma unroll
  for (int m = 0; m < 4; ++m)
#pragma unroll
    for (int n = 0; n < 4; ++n) acc[m][n] = (f32x4){0.f, 0.f, 0.f, 0.f};

  const char* aB = (const char*)xb;
  const char* bB = (const char*)wt;
  char* asmB = (char*)As;
  char* bsmB = (char*)Bs;
  int sw = (lr & 7) << 4;

  for (int k0 = 0; k0 < DIM; k0 += 64) {
#pragma unroll
    for (int i = 0; i < 4; ++i) {
      int off = (t + 256 * i) * 16;
      int row = off >> 7;
      int cb = off & 127;
      int scb = cb ^ ((row & 7) << 4);
      async16(aB + ((size_t)(bm * 128 + row) * DIM + k0) * 2 + scb, asmB + off);
      async16(bB + ((size_t)(bn * 128 + row) * DIM + k0) * 2 + scb, bsmB + off);
    }
    __syncthreads();
#pragma unroll
    for (int kk = 0; kk < 2; ++kk) {
      short8 af[4], bf[4];
#pragma unroll
      for (int m = 0; m < 4; ++m)
        af[m] = *(const short8*)(asmB + (wr * 64 + m * 16 + lr) * 128 +
                                 ((kk * 64 + kc * 16) ^ sw));
#pragma unroll
      for (int n = 0; n < 4; ++n)
        bf[n] = *(const short8*)(bsmB + (wc * 64 + n * 16 + lr) * 128 +
                                 ((kk * 64 + kc * 16) ^ sw));
#pragma unroll
      for (int m = 0; m < 4; ++m)
#pragma unroll
        for (int n = 0; n < 4; ++n)
          acc[m][n] = __builtin_amdgcn_mfma_f32_16x16x32_bf16(af[m], bf[n], acc[m][n], 0, 0, 0);
    }
    __syncthreads();
  }

  int lq = l >> 4;
  if (vmode) {
#pragma unroll
    for (int m = 0; m < 4; ++m)
#pragma unroll
      for (int n = 0; n < 4; ++n) {
        int gcol = bn * 128 + wc * 64 + n * 16 + lr;
        float bv = bias[gcol];
        int grow = bm * 128 + wr * 64 + m * 16 + lq * 4;
        ushort4 u;
        u.x = f2bf(acc[m][n][0] + bv);
        u.y = f2bf(acc[m][n][1] + bv);
        u.z = f2bf(acc[m][n][2] + bv);
        u.w = f2bf(acc[m][n][3] + bv);
        *(ushort4*)(out + (size_t)gcol * SEQ + grow) = u;
      }
  } else {
#pragma unroll
    for (int m = 0; m < 4; ++m)
#pragma unroll
      for (int n = 0; n < 4; ++n) {
        int gcol = bn * 128 + wc * 64 + n * 16 + lr;
        float bv = bias[gcol];
#pragma unroll
        for (int i = 0; i < 4; ++i) {
          int grow = bm * 128 + wr * 64 + m * 16 + lq * 4 + i;
          out[(size_t)grow * DIM + gcol] = f2bf(acc[m][n][i] + bv);
        }
      }
  }
}

// ---------------- RMSNorm + RoPE, in-place on bf16 ----------------
__global__ void k_normrope(unsigned short* __restrict__ qk, const float* __restrict__ cosb,
                           const float* __restrict__ sinb, const float* __restrict__ g,
                           float scale) {
  int t = threadIdx.x;
  int w = t >> 6, l = t & 63;
  int row = blockIdx.x * 4 + w;
  int s_idx = row / NHEAD, head = row % NHEAD;
  size_t base = (size_t)s_idx * DIM + head * HDIM;
  unsigned int pair = *(const unsigned int*)(qk + base + 2 * l);
  float x0 = bf2f((unsigned short)(pair & 0xffffu));
  float x1 = bf2f((unsigned short)(pair >> 16));
  float ss = x0 * x0 + x1 * x1;
#pragma unroll
  for (int off = 1; off < 64; off <<= 1) ss += __shfl_xor(ss, off);
  float r = rsqrtf(ss * (1.0f / 128.0f) + 1e-6f);
  float g0 = g[2 * l], g1 = g[2 * l + 1];
  float c0 = cosb[s_idx * HDIM + 2 * l], c1 = cosb[s_idx * HDIM + 2 * l + 1];
  float s0 = sinb[s_idx * HDIM + 2 * l], s1 = sinb[s_idx * HDIM + 2 * l + 1];
  float xn0 = x0 * r * g0, xn1 = x1 * r * g1;
  float o0 = (xn0 * c0 - xn1 * s0) * scale;
  float o1 = (xn1 * c1 + xn0 * s1) * scale;
  unsigned int po = (unsigned int)f2bf(o0) | ((unsigned int)f2bf(o1) << 16);
  *(unsigned int*)(qk + base + 2 * l) = po;
}

// ---------------- Flash attention, single-buffered, hoisted staging offsets ----------------
// q pre-scaled by (1/sqrt(128))*log2(e): softmax in exp2 domain.
__global__ __launch_bounds__(256) void k_attn(const unsigned short* __restrict__ q,
                                              const unsigned short* __restrict__ k,
                                              const unsigned short* __restrict__ vt,
                                              float* __restrict__ out) {
  __shared__ unsigned short Ksm[64 * 128];    // [kv][d], swizzled
  __shared__ unsigned short Vtsm[128 * 64];   // [d][kv], swizzled
  __shared__ unsigned short Psm[4][16 * 72];  // per-wave P
  int t = threadIdx.x;
  int w = t >> 6, l = t & 63;
  int lr = l & 15, lq = l >> 4;
  int fid = blockIdx.x;
  int logical = (fid & 7) * 96 + (fid >> 3);  // bijective: 768 = 8*96
  int qt = logical & 31, h = logical >> 5;
  int q0 = qt * 64 + w * 16;

  const char* kbase = (const char*)k + (size_t)h * HDIM * 2;
  const char* vbase = (const char*)vt + (size_t)h * HDIM * SEQ * 2;

  // hoisted per-thread staging offsets (swizzled source, linear LDS dest)
  int koff[4], voff[4], dst[4];
#pragma unroll
  for (int i = 0; i < 4; ++i) {
    int off = (t + 256 * i) * 16;
    dst[i] = off;
    {
      int row = off >> 8, cb = off & 255;
      koff[i] = row * (DIM * 2) + (cb ^ ((row & 7) << 4));
    }
    {
      int row = off >> 7, cb = off & 127;
      voff[i] = row * (SEQ * 2) + (cb ^ ((row & 7) << 4));
    }
  }

  short8 qf[4];
  {
    size_t qrow = (size_t)(q0 + lr) * DIM + h * HDIM;
#pragma unroll
    for (int kc = 0; kc < 4; ++kc) qf[kc] = *(const short8*)(q + qrow + kc * 32 + lq * 8);
  }

  f32x4 o[8];
#pragma unroll
  for (int dc = 0; dc < 8; ++dc) o[dc] = (f32x4){0.f, 0.f, 0.f, 0.f};
  float m_[4] = {-1e30f, -1e30f, -1e30f, -1e30f};
  float lsum[4] = {0.f, 0.f, 0.f, 0.f};

  for (int kt = 0; kt < 32; ++kt) {
    const char* kt_k = kbase + (size_t)kt * (64 * DIM * 2);
    const char* kt_v = vbase + kt * 128;
#pragma unroll
    for (int i = 0; i < 4; ++i) {
      async16(kt_k + koff[i], (char*)Ksm + dst[i]);
      async16(kt_v + voff[i], (char*)Vtsm + dst[i]);
    }
    __syncthreads();

    // S = Q K^T  (16 x 64 per wave)
    f32x4 s[4];
#pragma unroll
    for (int c = 0; c < 4; ++c) s[c] = (f32x4){0.f, 0.f, 0.f, 0.f};
    const char* Kc = (const char*)Ksm;
    __builtin_amdgcn_s_setprio(1);
#pragma unroll
    for (int c = 0; c < 4; ++c)
#pragma unroll
      for (int kc = 0; kc < 4; ++kc) {
        short8 kf = *(const short8*)(Kc + (c * 16 + lr) * 256 +
                                     ((kc * 64 + lq * 16) ^ ((lr & 7) << 4)));
        s[c] = __builtin_amdgcn_mfma_f32_16x16x32_bf16(qf[kc], kf, s[c], 0, 0, 0);
      }
    __builtin_amdgcn_s_setprio(0);

    // online softmax in exp2 domain
    float mt[4];
#pragma unroll
    for (int i = 0; i < 4; ++i) {
      float mm = fmaxf(fmaxf(s[0][i], s[1][i]), fmaxf(s[2][i], s[3][i]));
#pragma unroll
      for (int off = 1; off < 16; off <<= 1) mm = fmaxf(mm, __shfl_xor(mm, off));
      mt[i] = mm;
    }
    bool ok = (mt[0] <= m_[0] + 10.0f) && (mt[1] <= m_[1] + 10.0f) &&
              (mt[2] <= m_[2] + 10.0f) && (mt[3] <= m_[3] + 10.0f);
    if (!__all(ok)) {
#pragma unroll
      for (int i = 0; i < 4; ++i) {
        float mn = fmaxf(m_[i], mt[i]);
        float corr = exp2f(m_[i] - mn);
        m_[i] = mn;
        lsum[i] *= corr;
#pragma unroll
        for (int dc = 0; dc < 8; ++dc) o[dc][i] *= corr;
      }
    }
#pragma unroll
    for (int c = 0; c < 4; ++c)
#pragma unroll
      for (int i = 0; i < 4; ++i) s[c][i] = exp2f(s[c][i] - m_[i]);
#pragma unroll
    for (int i = 0; i < 4; ++i) {
      float rs = s[0][i] + s[1][i] + s[2][i] + s[3][i];
#pragma unroll
      for (int off = 1; off < 16; off <<= 1) rs += __shfl_xor(rs, off);
      lsum[i] += rs;
    }

    // P -> per-wave LDS via packed bf16 converts
    unsigned short* pw = Psm[w];
#pragma unroll
    for (int c = 0; c < 4; ++c) {
      __hip_bfloat162 p01 = __float22bfloat162_rn(make_float2(s[c][0], s[c][1]));
      __hip_bfloat162 p23 = __float22bfloat162_rn(make_float2(s[c][2], s[c][3]));
      unsigned int u01 = *(unsigned int*)&p01;
      unsigned int u23 = *(unsigned int*)&p23;
      pw[(lq * 4 + 0) * 72 + c * 16 + lr] = (unsigned short)(u01 & 0xffffu);
      pw[(lq * 4 + 1) * 72 + c * 16 + lr] = (unsigned short)(u01 >> 16);
      pw[(lq * 4 + 2) * 72 + c * 16 + lr] = (unsigned short)(u23 & 0xffffu);
      pw[(lq * 4 + 3) * 72 + c * 16 + lr] = (unsigned short)(u23 >> 16);
    }
    short8 pf[2];
#pragma unroll
    for (int kvc = 0; kvc < 2; ++kvc)
      pf[kvc] = *(const short8*)(pw + lr * 72 + kvc * 32 + lq * 8);

    // O += P V
    const char* Vc = (const char*)Vtsm;
    __builtin_amdgcn_s_setprio(1);
#pragma unroll
    for (int dc = 0; dc < 8; ++dc)
#pragma unroll
      for (int kvc = 0; kvc < 2; ++kvc) {
        short8 vf = *(const short8*)(Vc + (dc * 16 + lr) * 128 +
                                     ((kvc * 64 + lq * 16) ^ ((lr & 7) << 4)));
        o[dc] = __builtin_amdgcn_mfma_f32_16x16x32_bf16(pf[kvc], vf, o[dc], 0, 0, 0);
      }
    __builtin_amdgcn_s_setprio(0);

    __syncthreads();
  }

#pragma unroll
  for (int dc = 0; dc < 8; ++dc)
#pragma unroll
    for (int i = 0; i < 4; ++i) {
      int grow = q0 + lq * 4 + i;
      out[(size_t)grow * DIM + h * HDIM + dc * 16 + lr] = o[dc][i] / lsum[i];
    }
}

extern "C" void kernel_launch(void* const* d_in, const int* in_sizes, int n_in,
                              void* d_out, int out_size, void* d_ws, size_t ws_size,
                              hipStream_t stream) {
  const float* x = (const float*)d_in[0];
  const float* rope_cos = (const float*)d_in[1];
  const float* rope_sin = (const float*)d_in[2];
  const float* Wq = (const float*)d_in[3];
  const float* bq = (const float*)d_in[4];
  const float* Wk = (const float*)d_in[5];
  const float* bk = (const float*)d_in[6];
  const float* Wv = (const float*)d_in[7];
  const float* bv = (const float*)d_in[8];
  const float* gq = (const float*)d_in[9];
  const float* gk = (const float*)d_in[10];
  float* out = (float*)d_out;

  unsigned short* xb = (unsigned short*)d_ws;               // 2048*3072
  unsigned short* wt = xb + (size_t)SEQ * DIM;              // 3072*3072
  unsigned short* qb = wt + (size_t)DIM * DIM;              // 2048*3072
  unsigned short* kb = qb + (size_t)SEQ * DIM;
  unsigned short* vtb = kb + (size_t)SEQ * DIM;             // V directly in [h*128+d][s]

  k_cvt_x<<<3072, 256, 0, stream>>>(x, xb);

  dim3 tg(DIM / 64, DIM / 64);

  k_transpose<<<tg, 256, 0, stream>>>(Wq, wt);
  k_gemm<<<384, 256, 0, stream>>>(xb, wt, bq, qb, 0);
  k_transpose<<<tg, 256, 0, stream>>>(Wk, wt);
  k_gemm<<<384, 256, 0, stream>>>(xb, wt, bk, kb, 0);
  k_transpose<<<tg, 256, 0, stream>>>(Wv, wt);
  k_gemm<<<384, 256, 0, stream>>>(xb, wt, bv, vtb, 1);

  // q scale = (1/sqrt(128)) * log2(e)  -> exp2-domain softmax
  k_normrope<<<SEQ * NHEAD / 4, 256, 0, stream>>>(qb, rope_cos, rope_sin, gq, 0.12751744f);
  k_normrope<<<SEQ * NHEAD / 4, 256, 0, stream>>>(kb, rope_cos, rope_sin, gk, 1.0f);

  k_attn<<<SEQ / 64 * NHEAD, 256, 0, stream>>>(qb, kb, vtb, out);
}

// Round 5
// 329.381 us; speedup vs baseline: 1.1822x; 1.0665x over previous
//
#include <hip/hip_runtime.h>
#include <hip/hip_bf16.h>

typedef __attribute__((ext_vector_type(8))) short short8;
typedef __attribute__((ext_vector_type(4))) float f32x4;
typedef __attribute__((ext_vector_type(16))) float f32x16;

#define SEQ 2048
#define DIM 3072
#define NHEAD 24
#define HDIM 128

__device__ __forceinline__ unsigned short f2bf(float f) {
  unsigned int b = __float_as_uint(f);
  b += 0x7fffu + ((b >> 16) & 1u);
  return (unsigned short)(b >> 16);
}
__device__ __forceinline__ float bf2f(unsigned short u) {
  return __uint_as_float(((unsigned int)u) << 16);
}
__device__ __forceinline__ unsigned int pkbf(float a, float b) {
  __hip_bfloat162 h = __float22bfloat162_rn(make_float2(a, b));
  return *(unsigned int*)&h;
}

__device__ __forceinline__ void async16(const void* g, void* l) {
  __builtin_amdgcn_global_load_lds(
      (const __attribute__((address_space(1))) unsigned int*)g,
      (__attribute__((address_space(3))) unsigned int*)l, 16, 0, 0);
}

// ---------------- cast x (fp32 -> bf16), 8 elems/thread ----------------
__global__ void k_cvt_x(const float* __restrict__ x, unsigned short* __restrict__ xb) {
  int idx = (blockIdx.x * 256 + threadIdx.x) * 8;
  float4 a = *(const float4*)(x + idx);
  float4 b = *(const float4*)(x + idx + 4);
  short8 o;
  o[0] = (short)f2bf(a.x); o[1] = (short)f2bf(a.y);
  o[2] = (short)f2bf(a.z); o[3] = (short)f2bf(a.w);
  o[4] = (short)f2bf(b.x); o[5] = (short)f2bf(b.y);
  o[6] = (short)f2bf(b.z); o[7] = (short)f2bf(b.w);
  *(short8*)(xb + idx) = o;
}

// ---------------- transpose + cast W (K x N fp32) -> Wt (N x K bf16), 64x64 tiles ----------------
__global__ __launch_bounds__(256) void k_transpose(const float* __restrict__ w,
                                                   unsigned short* __restrict__ wt) {
  __shared__ unsigned short tile[64][68];
  int t = threadIdx.x;
  int c4 = (t & 15) * 4;
  int r0 = t >> 4;
  int n0 = blockIdx.x * 64, k0 = blockIdx.y * 64;
#pragma unroll
  for (int j = 0; j < 4; ++j) {
    int r = r0 + 16 * j;
    float4 v = *(const float4*)(w + (size_t)(k0 + r) * DIM + n0 + c4);
    ushort4 u;
    u.x = f2bf(v.x); u.y = f2bf(v.y); u.z = f2bf(v.z); u.w = f2bf(v.w);
    *(ushort4*)&tile[r][c4] = u;
  }
  __syncthreads();
#pragma unroll
  for (int j = 0; j < 4; ++j) {
    int nn = r0 + 16 * j;
    ushort4 u;
    u.x = tile[c4 + 0][nn]; u.y = tile[c4 + 1][nn];
    u.z = tile[c4 + 2][nn]; u.w = tile[c4 + 3][nn];
    *(ushort4*)(wt + (size_t)(n0 + nn) * DIM + k0 + c4) = u;
  }
}

// ---------------- GEMM: C(2048 x 3072) = xb @ Wt^T + bias, bf16 out ----------------
__global__ __launch_bounds__(256) void k_gemm(const unsigned short* __restrict__ xb,
                                              const unsigned short* __restrict__ wt,
                                              const float* __restrict__ bias,
                                              unsigned short* __restrict__ out,
                                              int vmode) {
  __shared__ unsigned short As[128 * 64];
  __shared__ unsigned short Bs[128 * 64];
  int t = threadIdx.x;
  int w = t >> 6, l = t & 63;
  int wr = w >> 1, wc = w & 1;
  int lr = l & 15, kc = l >> 4;
  int fid = blockIdx.x;
  int logical = (fid & 7) * 48 + (fid >> 3);  // bijective: 384 = 8*48
  int bm = logical & 15, bn = logical >> 4;

  f32x4 acc[4][4];
#pragma unroll
  for (int m = 0; m < 4; ++m)
#pragma unroll
    for (int n = 0; n < 4; ++n) acc[m][n] = (f32x4){0.f, 0.f, 0.f, 0.f};

  const char* aB = (const char*)xb;
  const char* bB = (const char*)wt;
  char* asmB = (char*)As;
  char* bsmB = (char*)Bs;
  int sw = (lr & 7) << 4;

  for (int k0 = 0; k0 < DIM; k0 += 64) {
#pragma unroll
    for (int i = 0; i < 4; ++i) {
      int off = (t + 256 * i) * 16;
      int row = off >> 7;
      int cb = off & 127;
      int scb = cb ^ ((row & 7) << 4);
      async16(aB + ((size_t)(bm * 128 + row) * DIM + k0) * 2 + scb, asmB + off);
      async16(bB + ((size_t)(bn * 128 + row) * DIM + k0) * 2 + scb, bsmB + off);
    }
    __syncthreads();
#pragma unroll
    for (int kk = 0; kk < 2; ++kk) {
      short8 af[4], bf[4];
#pragma unroll
      for (int m = 0; m < 4; ++m)
        af[m] = *(const short8*)(asmB + (wr * 64 + m * 16 + lr) * 128 +
                                 ((kk * 64 + kc * 16) ^ sw));
#pragma unroll
      for (int n = 0; n < 4; ++n)
        bf[n] = *(const short8*)(bsmB + (wc * 64 + n * 16 + lr) * 128 +
                                 ((kk * 64 + kc * 16) ^ sw));
#pragma unroll
      for (int m = 0; m < 4; ++m)
#pragma unroll
        for (int n = 0; n < 4; ++n)
          acc[m][n] = __builtin_amdgcn_mfma_f32_16x16x32_bf16(af[m], bf[n], acc[m][n], 0, 0, 0);
    }
    __syncthreads();
  }

  int lq = l >> 4;
  if (vmode) {
#pragma unroll
    for (int m = 0; m < 4; ++m)
#pragma unroll
      for (int n = 0; n < 4; ++n) {
        int gcol = bn * 128 + wc * 64 + n * 16 + lr;
        float bv = bias[gcol];
        int grow = bm * 128 + wr * 64 + m * 16 + lq * 4;
        ushort4 u;
        u.x = f2bf(acc[m][n][0] + bv);
        u.y = f2bf(acc[m][n][1] + bv);
        u.z = f2bf(acc[m][n][2] + bv);
        u.w = f2bf(acc[m][n][3] + bv);
        *(ushort4*)(out + (size_t)gcol * SEQ + grow) = u;
      }
  } else {
#pragma unroll
    for (int m = 0; m < 4; ++m)
#pragma unroll
      for (int n = 0; n < 4; ++n) {
        int gcol = bn * 128 + wc * 64 + n * 16 + lr;
        float bv = bias[gcol];
#pragma unroll
        for (int i = 0; i < 4; ++i) {
          int grow = bm * 128 + wr * 64 + m * 16 + lq * 4 + i;
          out[(size_t)grow * DIM + gcol] = f2bf(acc[m][n][i] + bv);
        }
      }
  }
}

// ---------------- RMSNorm + RoPE, in-place on bf16 ----------------
__global__ void k_normrope(unsigned short* __restrict__ qk, const float* __restrict__ cosb,
                           const float* __restrict__ sinb, const float* __restrict__ g,
                           float scale) {
  int t = threadIdx.x;
  int w = t >> 6, l = t & 63;
  int row = blockIdx.x * 4 + w;
  int s_idx = row / NHEAD, head = row % NHEAD;
  size_t base = (size_t)s_idx * DIM + head * HDIM;
  unsigned int pair = *(const unsigned int*)(qk + base + 2 * l);
  float x0 = bf2f((unsigned short)(pair & 0xffffu));
  float x1 = bf2f((unsigned short)(pair >> 16));
  float ss = x0 * x0 + x1 * x1;
#pragma unroll
  for (int off = 1; off < 64; off <<= 1) ss += __shfl_xor(ss, off);
  float r = rsqrtf(ss * (1.0f / 128.0f) + 1e-6f);
  float g0 = g[2 * l], g1 = g[2 * l + 1];
  float c0 = cosb[s_idx * HDIM + 2 * l], c1 = cosb[s_idx * HDIM + 2 * l + 1];
  float s0 = sinb[s_idx * HDIM + 2 * l], s1 = sinb[s_idx * HDIM + 2 * l + 1];
  float xn0 = x0 * r * g0, xn1 = x1 * r * g1;
  float o0 = (xn0 * c0 - xn1 * s0) * scale;
  float o1 = (xn1 * c1 + xn0 * s1) * scale;
  unsigned int po = (unsigned int)f2bf(o0) | ((unsigned int)f2bf(o1) << 16);
  *(unsigned int*)(qk + base + 2 * l) = po;
}

// ---------------- Flash attention: swapped-QK^T 32x32, in-register softmax ----------------
// 2 waves x 32 q-rows per block, 768 blocks. Per wave: S^T = mfma(K, Q) so each
// lane owns one q-row (col = lane&31); P->A-frag via pkbf + v_permlane32_swap_b32.
// q pre-scaled by (1/sqrt(128))*log2(e): exp2-domain softmax.
__global__ __launch_bounds__(128, 2) void k_attn(const unsigned short* __restrict__ q,
                                                 const unsigned short* __restrict__ k,
                                                 const unsigned short* __restrict__ vt,
                                                 float* __restrict__ out) {
  __shared__ unsigned short Ksm[64 * 128];   // [kv][d], 4-bit swizzle
  __shared__ unsigned short Vtsm[128 * 64];  // [d][kv], 3-bit swizzle
  int t = threadIdx.x;       // 0..127
  int w = t >> 6, l = t & 63;
  int q32 = l & 31, hi = l >> 5;
  int hi4 = hi * 4;
  int fid = blockIdx.x;
  int logical = (fid & 7) * 96 + (fid >> 3);  // bijective: 768 = 8*96
  int qt = logical & 31, h = logical >> 5;
  int q0w = qt * 64 + w * 32;

  const char* kbase = (const char*)k + (size_t)h * HDIM * 2;
  const char* vbase = (const char*)vt + (size_t)h * HDIM * SEQ * 2;

  // hoisted staging offsets: linear LDS dest, pre-swizzled global source
  int koff[8], voff[8];
#pragma unroll
  for (int i = 0; i < 8; ++i) {
    int off = (t + 128 * i) * 16;
    int krow = off >> 8, kcb = off & 255;
    koff[i] = krow * (DIM * 2) + (kcb ^ ((krow & 15) << 4));
    int vrow = off >> 7, vcb = off & 127;
    voff[i] = vrow * (SEQ * 2) + (vcb ^ ((vrow & 7) << 4));
  }

  // Q row in registers: lane owns q-row q0w+q32; frag ks covers d = ks*16+hi*8..+7
  short8 qf[8];
  {
    const unsigned short* qrow = q + (size_t)(q0w + q32) * DIM + h * HDIM;
#pragma unroll
    for (int ks = 0; ks < 8; ++ks) qf[ks] = *(const short8*)(qrow + ks * 16 + hi * 8);
  }

  f32x16 o0 = {0.f,0.f,0.f,0.f,0.f,0.f,0.f,0.f,0.f,0.f,0.f,0.f,0.f,0.f,0.f,0.f};
  f32x16 o1 = o0, o2 = o0, o3 = o0;
  float m_ = -1e30f, lsum = 0.f;
  int ksw = (q32 & 15) << 4;
  int vsw = (q32 & 7) << 4;

  union U8 { short8 s8; unsigned int u[4]; };

  for (int kt = 0; kt < 32; ++kt) {
    const char* kt_k = kbase + (size_t)kt * (64 * DIM * 2);
    const char* kt_v = vbase + kt * 128;
#pragma unroll
    for (int i = 0; i < 8; ++i) {
      int dst = (t + 128 * i) * 16;
      async16(kt_k + koff[i], (char*)Ksm + dst);
      async16(kt_v + voff[i], (char*)Vtsm + dst);
    }
    __syncthreads();

    // S^T = K Q^T: two 32x32 chunks (k rows 0..31, 32..63)
    f32x16 st0 = {0.f,0.f,0.f,0.f,0.f,0.f,0.f,0.f,0.f,0.f,0.f,0.f,0.f,0.f,0.f,0.f};
    f32x16 st1 = st0;
    {
      const char* kr0 = (const char*)Ksm + q32 * 256;
      const char* kr1 = (const char*)Ksm + (32 + q32) * 256;
      __builtin_amdgcn_s_setprio(1);
#pragma unroll
      for (int ks = 0; ks < 8; ++ks) {
        int cb = (ks * 32 + hi * 16) ^ ksw;
        short8 kf0 = *(const short8*)(kr0 + cb);
        short8 kf1 = *(const short8*)(kr1 + cb);
        st0 = __builtin_amdgcn_mfma_f32_32x32x16_bf16(kf0, qf[ks], st0, 0, 0, 0);
        st1 = __builtin_amdgcn_mfma_f32_32x32x16_bf16(kf1, qf[ks], st1, 0, 0, 0);
      }
      __builtin_amdgcn_s_setprio(0);
    }

    // row max (lane owns q-row): 31 in-lane fmax + 1 cross-half exchange
    float mx = fmaxf(st0[0], st1[0]);
#pragma unroll
    for (int r = 1; r < 16; ++r) mx = fmaxf(mx, fmaxf(st0[r], st1[r]));
    mx = fmaxf(mx, __shfl_xor(mx, 32));

    if (__any(mx > m_ + 10.0f)) {  // rescale (rare after first tile)
      float mn = fmaxf(m_, mx);
      float corr = exp2f(m_ - mn);
      m_ = mn;
      lsum *= corr;
#pragma unroll
      for (int r = 0; r < 16; ++r) {
        float cr = __shfl(corr, (r & 3) + 8 * (r >> 2) + hi4);
        o0[r] *= cr; o1[r] *= cr; o2[r] *= cr; o3[r] *= cr;
      }
    }

#pragma unroll
    for (int r = 0; r < 16; ++r) {
      st0[r] = exp2f(st0[r] - m_);
      st1[r] = exp2f(st1[r] - m_);
    }
    {
      float sm = st0[0] + st1[0];
#pragma unroll
      for (int r = 1; r < 16; ++r) sm += st0[r] + st1[r];
      sm += __shfl_xor(sm, 32);
      lsum += sm;
    }

    // P -> A-fragments in-register: pkbf pairs + permlane32_swap
    U8 pa[4];
#pragma unroll
    for (int b = 0; b < 4; ++b) {  // b = chunk*2 + half
      unsigned int a0, a1, a2, a3;
      if (b < 2) {
        int r0 = (b & 1) * 8;
        a0 = pkbf(st0[r0 + 0], st0[r0 + 1]);
        a1 = pkbf(st0[r0 + 2], st0[r0 + 3]);
        a2 = pkbf(st0[r0 + 4], st0[r0 + 5]);
        a3 = pkbf(st0[r0 + 6], st0[r0 + 7]);
      } else {
        int r0 = (b & 1) * 8;
        a0 = pkbf(st1[r0 + 0], st1[r0 + 1]);
        a1 = pkbf(st1[r0 + 2], st1[r0 + 3]);
        a2 = pkbf(st1[r0 + 4], st1[r0 + 5]);
        a3 = pkbf(st1[r0 + 6], st1[r0 + 7]);
      }
      asm volatile("v_permlane32_swap_b32 %0, %1" : "+v"(a0), "+v"(a2));
      asm volatile("v_permlane32_swap_b32 %0, %1" : "+v"(a1), "+v"(a3));
      pa[b].u[0] = a0; pa[b].u[1] = a1; pa[b].u[2] = a2; pa[b].u[3] = a3;
    }

    // O += P V  (4 d-tiles of 32)
    __builtin_amdgcn_s_setprio(1);
#pragma unroll
    for (int ks = 0; ks < 4; ++ks) {
      int cb = (ks * 32 + hi * 16) ^ vsw;
      short8 vf0 = *(const short8*)((const char*)Vtsm + (0 * 32 + q32) * 128 + cb);
      short8 vf1 = *(const short8*)((const char*)Vtsm + (1 * 32 + q32) * 128 + cb);
      short8 vf2 = *(const short8*)((const char*)Vtsm + (2 * 32 + q32) * 128 + cb);
      short8 vf3 = *(const short8*)((const char*)Vtsm + (3 * 32 + q32) * 128 + cb);
      o0 = __builtin_amdgcn_mfma_f32_32x32x16_bf16(pa[ks].s8, vf0, o0, 0, 0, 0);
      o1 = __builtin_amdgcn_mfma_f32_32x32x16_bf16(pa[ks].s8, vf1, o1, 0, 0, 0);
      o2 = __builtin_amdgcn_mfma_f32_32x32x16_bf16(pa[ks].s8, vf2, o2, 0, 0, 0);
      o3 = __builtin_amdgcn_mfma_f32_32x32x16_bf16(pa[ks].s8, vf3, o3, 0, 0, 0);
    }
    __builtin_amdgcn_s_setprio(0);

    __syncthreads();
  }

  float inv = 1.0f / lsum;
#pragma unroll
  for (int r = 0; r < 16; ++r) {
    float fr = __shfl(inv, (r & 3) + 8 * (r >> 2) + hi4);
    int grow = q0w + (r & 3) + 8 * (r >> 2) + hi4;
    float* orow = out + (size_t)grow * DIM + h * HDIM + q32;
    orow[0]  = o0[r] * fr;
    orow[32] = o1[r] * fr;
    orow[64] = o2[r] * fr;
    orow[96] = o3[r] * fr;
  }
}

extern "C" void kernel_launch(void* const* d_in, const int* in_sizes, int n_in,
                              void* d_out, int out_size, void* d_ws, size_t ws_size,
                              hipStream_t stream) {
  const float* x = (const float*)d_in[0];
  const float* rope_cos = (const float*)d_in[1];
  const float* rope_sin = (const float*)d_in[2];
  const float* Wq = (const float*)d_in[3];
  const float* bq = (const float*)d_in[4];
  const float* Wk = (const float*)d_in[5];
  const float* bk = (const float*)d_in[6];
  const float* Wv = (const float*)d_in[7];
  const float* bv = (const float*)d_in[8];
  const float* gq = (const float*)d_in[9];
  const float* gk = (const float*)d_in[10];
  float* out = (float*)d_out;

  unsigned short* xb = (unsigned short*)d_ws;               // 2048*3072
  unsigned short* wt = xb + (size_t)SEQ * DIM;              // 3072*3072
  unsigned short* qb = wt + (size_t)DIM * DIM;              // 2048*3072
  unsigned short* kb = qb + (size_t)SEQ * DIM;
  unsigned short* vtb = kb + (size_t)SEQ * DIM;             // V directly in [h*128+d][s]

  k_cvt_x<<<3072, 256, 0, stream>>>(x, xb);

  dim3 tg(DIM / 64, DIM / 64);

  k_transpose<<<tg, 256, 0, stream>>>(Wq, wt);
  k_gemm<<<384, 256, 0, stream>>>(xb, wt, bq, qb, 0);
  k_transpose<<<tg, 256, 0, stream>>>(Wk, wt);
  k_gemm<<<384, 256, 0, stream>>>(xb, wt, bk, kb, 0);
  k_transpose<<<tg, 256, 0, stream>>>(Wv, wt);
  k_gemm<<<384, 256, 0, stream>>>(xb, wt, bv, vtb, 1);

  // q scale = (1/sqrt(128)) * log2(e)  -> exp2-domain softmax
  k_normrope<<<SEQ * NHEAD / 4, 256, 0, stream>>>(qb, rope_cos, rope_sin, gq, 0.12751744f);
  k_normrope<<<SEQ * NHEAD / 4, 256, 0, stream>>>(kb, rope_cos, rope_sin, gk, 1.0f);

  k_attn<<<768, 128, 0, stream>>>(qb, kb, vtb, out);
}

// Round 6
// 317.865 us; speedup vs baseline: 1.2251x; 1.0362x over previous
//
#include <hip/hip_runtime.h>
#include <hip/hip_bf16.h>

typedef __attribute__((ext_vector_type(8))) short short8;
typedef __attribute__((ext_vector_type(4))) float f32x4;
typedef __attribute__((ext_vector_type(16))) float f32x16;

#define SEQ 2048
#define DIM 3072
#define NHEAD 24
#define HDIM 128

__device__ __forceinline__ unsigned short f2bf(float f) {
  unsigned int b = __float_as_uint(f);
  b += 0x7fffu + ((b >> 16) & 1u);
  return (unsigned short)(b >> 16);
}
__device__ __forceinline__ float bf2f(unsigned short u) {
  return __uint_as_float(((unsigned int)u) << 16);
}
__device__ __forceinline__ unsigned int pkbf(float a, float b) {
  __hip_bfloat162 h = __float22bfloat162_rn(make_float2(a, b));
  return *(unsigned int*)&h;
}

__device__ __forceinline__ void async16(const void* g, void* l) {
  __builtin_amdgcn_global_load_lds(
      (const __attribute__((address_space(1))) unsigned int*)g,
      (__attribute__((address_space(3))) unsigned int*)l, 16, 0, 0);
}

// ---------------- cast x (fp32 -> bf16), 8 elems/thread ----------------
__global__ void k_cvt_x(const float* __restrict__ x, unsigned short* __restrict__ xb) {
  int idx = (blockIdx.x * 256 + threadIdx.x) * 8;
  float4 a = *(const float4*)(x + idx);
  float4 b = *(const float4*)(x + idx + 4);
  short8 o;
  o[0] = (short)f2bf(a.x); o[1] = (short)f2bf(a.y);
  o[2] = (short)f2bf(a.z); o[3] = (short)f2bf(a.w);
  o[4] = (short)f2bf(b.x); o[5] = (short)f2bf(b.y);
  o[6] = (short)f2bf(b.z); o[7] = (short)f2bf(b.w);
  *(short8*)(xb + idx) = o;
}

// ---------------- transpose + cast one W (K x N fp32) -> Wt rows (N x K bf16) ----------------
__device__ __forceinline__ void transpose_tile(const float* __restrict__ w,
                                               unsigned short* __restrict__ wt,
                                               int n0, int k0, int outRowBase, int t) {
  __shared__ unsigned short tile[64][68];
  int c4 = (t & 15) * 4;
  int r0 = t >> 4;
#pragma unroll
  for (int j = 0; j < 4; ++j) {
    int r = r0 + 16 * j;
    float4 v = *(const float4*)(w + (size_t)(k0 + r) * DIM + n0 + c4);
    ushort4 u;
    u.x = f2bf(v.x); u.y = f2bf(v.y); u.z = f2bf(v.z); u.w = f2bf(v.w);
    *(ushort4*)&tile[r][c4] = u;
  }
  __syncthreads();
#pragma unroll
  for (int j = 0; j < 4; ++j) {
    int nn = r0 + 16 * j;
    ushort4 u;
    u.x = tile[c4 + 0][nn]; u.y = tile[c4 + 1][nn];
    u.z = tile[c4 + 2][nn]; u.w = tile[c4 + 3][nn];
    *(ushort4*)(wt + (size_t)(outRowBase + n0 + nn) * DIM + k0 + c4) = u;
  }
}

__global__ __launch_bounds__(256) void k_transpose(const float* __restrict__ w,
                                                   unsigned short* __restrict__ wt) {
  transpose_tile(w, wt, blockIdx.x * 64, blockIdx.y * 64, 0, threadIdx.x);
}

__global__ __launch_bounds__(256) void k_transpose3(const float* __restrict__ w0,
                                                    const float* __restrict__ w1,
                                                    const float* __restrict__ w2,
                                                    unsigned short* __restrict__ wt) {
  const float* w = blockIdx.z == 0 ? w0 : (blockIdx.z == 1 ? w1 : w2);
  transpose_tile(w, wt, blockIdx.x * 64, blockIdx.y * 64, blockIdx.z * DIM, threadIdx.x);
}

// ---------------- GEMM core: one 128x128 tile, BK=64, T2 swizzle ----------------
__device__ __forceinline__ void gemm_tile(const unsigned short* __restrict__ xb,
                                          const unsigned short* __restrict__ wt,
                                          int bm, int bn, int t, f32x4 (&acc)[4][4],
                                          unsigned short* As, unsigned short* Bs) {
  int l = t & 63, w = t >> 6;
  int wr = w >> 1, wc = w & 1;
  int lr = l & 15, kc = l >> 4;
  const char* aB = (const char*)xb;
  const char* bB = (const char*)wt;
  char* asmB = (char*)As;
  char* bsmB = (char*)Bs;
  int sw = (lr & 7) << 4;

  for (int k0 = 0; k0 < DIM; k0 += 64) {
#pragma unroll
    for (int i = 0; i < 4; ++i) {
      int off = (t + 256 * i) * 16;
      int row = off >> 7;
      int cb = off & 127;
      int scb = cb ^ ((row & 7) << 4);
      async16(aB + ((size_t)(bm * 128 + row) * DIM + k0) * 2 + scb, asmB + off);
      async16(bB + ((size_t)(bn * 128 + row) * DIM + k0) * 2 + scb, bsmB + off);
    }
    __syncthreads();
#pragma unroll
    for (int kk = 0; kk < 2; ++kk) {
      short8 af[4], bf[4];
#pragma unroll
      for (int m = 0; m < 4; ++m)
        af[m] = *(const short8*)(asmB + (wr * 64 + m * 16 + lr) * 128 +
                                 ((kk * 64 + kc * 16) ^ sw));
#pragma unroll
      for (int n = 0; n < 4; ++n)
        bf[n] = *(const short8*)(bsmB + (wc * 64 + n * 16 + lr) * 128 +
                                 ((kk * 64 + kc * 16) ^ sw));
#pragma unroll
      for (int m = 0; m < 4; ++m)
#pragma unroll
        for (int n = 0; n < 4; ++n)
          acc[m][n] = __builtin_amdgcn_mfma_f32_16x16x32_bf16(af[m], bf[n], acc[m][n], 0, 0, 0);
    }
    __syncthreads();
  }
}

// ---------------- fallback GEMM (one W at a time) ----------------
__global__ __launch_bounds__(256) void k_gemm(const unsigned short* __restrict__ xb,
                                              const unsigned short* __restrict__ wt,
                                              const float* __restrict__ bias,
                                              unsigned short* __restrict__ out,
                                              int vmode) {
  __shared__ unsigned short As[128 * 64];
  __shared__ unsigned short Bs[128 * 64];
  int t = threadIdx.x;
  int fid = blockIdx.x;
  int logical = (fid & 7) * 48 + (fid >> 3);  // bijective: 384 = 8*48
  int bm = logical & 15, bn = logical >> 4;

  f32x4 acc[4][4];
#pragma unroll
  for (int m = 0; m < 4; ++m)
#pragma unroll
    for (int n = 0; n < 4; ++n) acc[m][n] = (f32x4){0.f, 0.f, 0.f, 0.f};

  gemm_tile(xb, wt, bm, bn, t, acc, As, Bs);

  int l = t & 63, w = t >> 6;
  int wr = w >> 1, wc = w & 1;
  int lr = l & 15, lq = l >> 4;
  if (vmode) {
#pragma unroll
    for (int m = 0; m < 4; ++m)
#pragma unroll
      for (int n = 0; n < 4; ++n) {
        int gcol = bn * 128 + wc * 64 + n * 16 + lr;
        float bv = bias[gcol];
        int grow = bm * 128 + wr * 64 + m * 16 + lq * 4;
        ushort4 u;
        u.x = f2bf(acc[m][n][0] + bv);
        u.y = f2bf(acc[m][n][1] + bv);
        u.z = f2bf(acc[m][n][2] + bv);
        u.w = f2bf(acc[m][n][3] + bv);
        *(ushort4*)(out + (size_t)gcol * SEQ + grow) = u;
      }
  } else {
#pragma unroll
    for (int m = 0; m < 4; ++m)
#pragma unroll
      for (int n = 0; n < 4; ++n) {
        int gcol = bn * 128 + wc * 64 + n * 16 + lr;
        float bv = bias[gcol];
#pragma unroll
        for (int i = 0; i < 4; ++i) {
          int grow = bm * 128 + wr * 64 + m * 16 + lq * 4 + i;
          out[(size_t)grow * DIM + gcol] = f2bf(acc[m][n][i] + bv);
        }
      }
  }
}

// ---------------- fused GEMM: C(2048 x 9216) = xb @ [Wq|Wk|Wv]^T, routed epilogue ----------------
__global__ __launch_bounds__(256) void k_gemm3(const unsigned short* __restrict__ xb,
                                               const unsigned short* __restrict__ wt,
                                               const float* __restrict__ bq,
                                               const float* __restrict__ bk,
                                               const float* __restrict__ bv,
                                               unsigned short* __restrict__ qb,
                                               unsigned short* __restrict__ kb,
                                               unsigned short* __restrict__ vtb) {
  __shared__ unsigned short As[128 * 64];
  __shared__ unsigned short Bs[128 * 64];
  int t = threadIdx.x;
  int fid = blockIdx.x;
  int logical = (fid & 7) * 144 + (fid >> 3);  // bijective: 1152 = 8*144
  int bm = logical & 15, bn = logical >> 4;    // bm 0..15, bn 0..71

  f32x4 acc[4][4];
#pragma unroll
  for (int m = 0; m < 4; ++m)
#pragma unroll
    for (int n = 0; n < 4; ++n) acc[m][n] = (f32x4){0.f, 0.f, 0.f, 0.f};

  gemm_tile(xb, wt, bm, bn, t, acc, As, Bs);

  int l = t & 63, w = t >> 6;
  int wr = w >> 1, wc = w & 1;
  int lr = l & 15, lq = l >> 4;

  int region = bn >= 48 ? 2 : (bn >= 24 ? 1 : 0);
  int bnl = bn - region * 24;
  const float* bias = region == 0 ? bq : (region == 1 ? bk : bv);

  if (region == 2) {  // V: transposed write into vtb[d_global][s]
#pragma unroll
    for (int m = 0; m < 4; ++m)
#pragma unroll
      for (int n = 0; n < 4; ++n) {
        int gcol = bnl * 128 + wc * 64 + n * 16 + lr;
        float bv_ = bias[gcol];
        int grow = bm * 128 + wr * 64 + m * 16 + lq * 4;
        ushort4 u;
        u.x = f2bf(acc[m][n][0] + bv_);
        u.y = f2bf(acc[m][n][1] + bv_);
        u.z = f2bf(acc[m][n][2] + bv_);
        u.w = f2bf(acc[m][n][3] + bv_);
        *(ushort4*)(vtb + (size_t)gcol * SEQ + grow) = u;
      }
  } else {
    unsigned short* outp = region == 0 ? qb : kb;
#pragma unroll
    for (int m = 0; m < 4; ++m)
#pragma unroll
      for (int n = 0; n < 4; ++n) {
        int gcol = bnl * 128 + wc * 64 + n * 16 + lr;
        float bv_ = bias[gcol];
#pragma unroll
        for (int i = 0; i < 4; ++i) {
          int grow = bm * 128 + wr * 64 + m * 16 + lq * 4 + i;
          outp[(size_t)grow * DIM + gcol] = f2bf(acc[m][n][i] + bv_);
        }
      }
  }
}

// ---------------- RMSNorm + RoPE body ----------------
__device__ __forceinline__ void normrope_row(unsigned short* __restrict__ buf, int row,
                                             const float* __restrict__ cosb,
                                             const float* __restrict__ sinb,
                                             const float* __restrict__ g, float scale, int l) {
  int s_idx = row / NHEAD, head = row % NHEAD;
  size_t base = (size_t)s_idx * DIM + head * HDIM;
  unsigned int pair = *(const unsigned int*)(buf + base + 2 * l);
  float x0 = bf2f((unsigned short)(pair & 0xffffu));
  float x1 = bf2f((unsigned short)(pair >> 16));
  float ss = x0 * x0 + x1 * x1;
#pragma unroll
  for (int off = 1; off < 64; off <<= 1) ss += __shfl_xor(ss, off);
  float r = rsqrtf(ss * (1.0f / 128.0f) + 1e-6f);
  float g0 = g[2 * l], g1 = g[2 * l + 1];
  float c0 = cosb[s_idx * HDIM + 2 * l], c1 = cosb[s_idx * HDIM + 2 * l + 1];
  float s0 = sinb[s_idx * HDIM + 2 * l], s1 = sinb[s_idx * HDIM + 2 * l + 1];
  float xn0 = x0 * r * g0, xn1 = x1 * r * g1;
  float o0 = (xn0 * c0 - xn1 * s0) * scale;
  float o1 = (xn1 * c1 + xn0 * s1) * scale;
  unsigned int po = (unsigned int)f2bf(o0) | ((unsigned int)f2bf(o1) << 16);
  *(unsigned int*)(buf + base + 2 * l) = po;
}

__global__ void k_normrope(unsigned short* __restrict__ qk, const float* __restrict__ cosb,
                           const float* __restrict__ sinb, const float* __restrict__ g,
                           float scale) {
  int t = threadIdx.x;
  normrope_row(qk, blockIdx.x * 4 + (t >> 6), cosb, sinb, g, scale, t & 63);
}

// fused q+k normrope: first half of grid -> q, second -> k
__global__ void k_normrope2(unsigned short* __restrict__ qb, unsigned short* __restrict__ kb,
                            const float* __restrict__ cosb, const float* __restrict__ sinb,
                            const float* __restrict__ gq, const float* __restrict__ gk) {
  int t = threadIdx.x;
  int row = blockIdx.x * 4 + (t >> 6);
  if (row < SEQ * NHEAD)
    normrope_row(qb, row, cosb, sinb, gq, 0.12751744f, t & 63);
  else
    normrope_row(kb, row - SEQ * NHEAD, cosb, sinb, gk, 1.0f, t & 63);
}

// ---------------- Flash attention: swapped-QK^T 32x32, in-register softmax ----------------
__global__ __launch_bounds__(128, 2) void k_attn(const unsigned short* __restrict__ q,
                                                 const unsigned short* __restrict__ k,
                                                 const unsigned short* __restrict__ vt,
                                                 float* __restrict__ out) {
  __shared__ unsigned short Ksm[64 * 128];   // [kv][d], 4-bit swizzle
  __shared__ unsigned short Vtsm[128 * 64];  // [d][kv], 3-bit swizzle
  int t = threadIdx.x;       // 0..127
  int w = t >> 6, l = t & 63;
  int q32 = l & 31, hi = l >> 5;
  int hi4 = hi * 4;
  int fid = blockIdx.x;
  int logical = (fid & 7) * 96 + (fid >> 3);  // bijective: 768 = 8*96
  int qt = logical & 31, h = logical >> 5;
  int q0w = qt * 64 + w * 32;

  const char* kbase = (const char*)k + (size_t)h * HDIM * 2;
  const char* vbase = (const char*)vt + (size_t)h * HDIM * SEQ * 2;

  int koff[8], voff[8];
#pragma unroll
  for (int i = 0; i < 8; ++i) {
    int off = (t + 128 * i) * 16;
    int krow = off >> 8, kcb = off & 255;
    koff[i] = krow * (DIM * 2) + (kcb ^ ((krow & 15) << 4));
    int vrow = off >> 7, vcb = off & 127;
    voff[i] = vrow * (SEQ * 2) + (vcb ^ ((vrow & 7) << 4));
  }

  short8 qf[8];
  {
    const unsigned short* qrow = q + (size_t)(q0w + q32) * DIM + h * HDIM;
#pragma unroll
    for (int ks = 0; ks < 8; ++ks) qf[ks] = *(const short8*)(qrow + ks * 16 + hi * 8);
  }

  f32x16 o0 = {0.f,0.f,0.f,0.f,0.f,0.f,0.f,0.f,0.f,0.f,0.f,0.f,0.f,0.f,0.f,0.f};
  f32x16 o1 = o0, o2 = o0, o3 = o0;
  float m_ = -1e30f, lsum = 0.f;
  int ksw = (q32 & 15) << 4;
  int vsw = (q32 & 7) << 4;

  union U8 { short8 s8; unsigned int u[4]; };

  for (int kt = 0; kt < 32; ++kt) {
    const char* kt_k = kbase + (size_t)kt * (64 * DIM * 2);
    const char* kt_v = vbase + kt * 128;
#pragma unroll
    for (int i = 0; i < 8; ++i) {
      int dst = (t + 128 * i) * 16;
      async16(kt_k + koff[i], (char*)Ksm + dst);
      async16(kt_v + voff[i], (char*)Vtsm + dst);
    }
    __syncthreads();

    f32x16 st0 = {0.f,0.f,0.f,0.f,0.f,0.f,0.f,0.f,0.f,0.f,0.f,0.f,0.f,0.f,0.f,0.f};
    f32x16 st1 = st0;
    {
      const char* kr0 = (const char*)Ksm + q32 * 256;
      const char* kr1 = (const char*)Ksm + (32 + q32) * 256;
      __builtin_amdgcn_s_setprio(1);
#pragma unroll
      for (int ks = 0; ks < 8; ++ks) {
        int cb = (ks * 32 + hi * 16) ^ ksw;
        short8 kf0 = *(const short8*)(kr0 + cb);
        short8 kf1 = *(const short8*)(kr1 + cb);
        st0 = __builtin_amdgcn_mfma_f32_32x32x16_bf16(kf0, qf[ks], st0, 0, 0, 0);
        st1 = __builtin_amdgcn_mfma_f32_32x32x16_bf16(kf1, qf[ks], st1, 0, 0, 0);
      }
      __builtin_amdgcn_s_setprio(0);
    }

    float mx = fmaxf(st0[0], st1[0]);
#pragma unroll
    for (int r = 1; r < 16; ++r) mx = fmaxf(mx, fmaxf(st0[r], st1[r]));
    mx = fmaxf(mx, __shfl_xor(mx, 32));

    if (__any(mx > m_ + 10.0f)) {
      float mn = fmaxf(m_, mx);
      float corr = exp2f(m_ - mn);
      m_ = mn;
      lsum *= corr;
#pragma unroll
      for (int r = 0; r < 16; ++r) {
        float cr = __shfl(corr, (r & 3) + 8 * (r >> 2) + hi4);
        o0[r] *= cr; o1[r] *= cr; o2[r] *= cr; o3[r] *= cr;
      }
    }

#pragma unroll
    for (int r = 0; r < 16; ++r) {
      st0[r] = exp2f(st0[r] - m_);
      st1[r] = exp2f(st1[r] - m_);
    }
    {
      float sm = st0[0] + st1[0];
#pragma unroll
      for (int r = 1; r < 16; ++r) sm += st0[r] + st1[r];
      sm += __shfl_xor(sm, 32);
      lsum += sm;
    }

    U8 pa[4];
#pragma unroll
    for (int b = 0; b < 4; ++b) {
      unsigned int a0, a1, a2, a3;
      if (b < 2) {
        int r0 = (b & 1) * 8;
        a0 = pkbf(st0[r0 + 0], st0[r0 + 1]);
        a1 = pkbf(st0[r0 + 2], st0[r0 + 3]);
        a2 = pkbf(st0[r0 + 4], st0[r0 + 5]);
        a3 = pkbf(st0[r0 + 6], st0[r0 + 7]);
      } else {
        int r0 = (b & 1) * 8;
        a0 = pkbf(st1[r0 + 0], st1[r0 + 1]);
        a1 = pkbf(st1[r0 + 2], st1[r0 + 3]);
        a2 = pkbf(st1[r0 + 4], st1[r0 + 5]);
        a3 = pkbf(st1[r0 + 6], st1[r0 + 7]);
      }
      asm volatile("v_permlane32_swap_b32 %0, %1" : "+v"(a0), "+v"(a2));
      asm volatile("v_permlane32_swap_b32 %0, %1" : "+v"(a1), "+v"(a3));
      pa[b].u[0] = a0; pa[b].u[1] = a1; pa[b].u[2] = a2; pa[b].u[3] = a3;
    }

    __builtin_amdgcn_s_setprio(1);
#pragma unroll
    for (int ks = 0; ks < 4; ++ks) {
      int cb = (ks * 32 + hi * 16) ^ vsw;
      short8 vf0 = *(const short8*)((const char*)Vtsm + (0 * 32 + q32) * 128 + cb);
      short8 vf1 = *(const short8*)((const char*)Vtsm + (1 * 32 + q32) * 128 + cb);
      short8 vf2 = *(const short8*)((const char*)Vtsm + (2 * 32 + q32) * 128 + cb);
      short8 vf3 = *(const short8*)((const char*)Vtsm + (3 * 32 + q32) * 128 + cb);
      o0 = __builtin_amdgcn_mfma_f32_32x32x16_bf16(pa[ks].s8, vf0, o0, 0, 0, 0);
      o1 = __builtin_amdgcn_mfma_f32_32x32x16_bf16(pa[ks].s8, vf1, o1, 0, 0, 0);
      o2 = __builtin_amdgcn_mfma_f32_32x32x16_bf16(pa[ks].s8, vf2, o2, 0, 0, 0);
      o3 = __builtin_amdgcn_mfma_f32_32x32x16_bf16(pa[ks].s8, vf3, o3, 0, 0, 0);
    }
    __builtin_amdgcn_s_setprio(0);

    __syncthreads();
  }

  float inv = 1.0f / lsum;
#pragma unroll
  for (int r = 0; r < 16; ++r) {
    float fr = __shfl(inv, (r & 3) + 8 * (r >> 2) + hi4);
    int grow = q0w + (r & 3) + 8 * (r >> 2) + hi4;
    float* orow = out + (size_t)grow * DIM + h * HDIM + q32;
    orow[0]  = o0[r] * fr;
    orow[32] = o1[r] * fr;
    orow[64] = o2[r] * fr;
    orow[96] = o3[r] * fr;
  }
}

extern "C" void kernel_launch(void* const* d_in, const int* in_sizes, int n_in,
                              void* d_out, int out_size, void* d_ws, size_t ws_size,
                              hipStream_t stream) {
  const float* x = (const float*)d_in[0];
  const float* rope_cos = (const float*)d_in[1];
  const float* rope_sin = (const float*)d_in[2];
  const float* Wq = (const float*)d_in[3];
  const float* bq = (const float*)d_in[4];
  const float* Wk = (const float*)d_in[5];
  const float* bk = (const float*)d_in[6];
  const float* Wv = (const float*)d_in[7];
  const float* bv = (const float*)d_in[8];
  const float* gq = (const float*)d_in[9];
  const float* gk = (const float*)d_in[10];
  float* out = (float*)d_out;

  const size_t slab = (size_t)SEQ * DIM;          // bf16 elements
  const size_t wt9elems = (size_t)3 * DIM * DIM;  // fused W^T
  const size_t need = (4 * slab + wt9elems) * 2;  // bytes

  if (ws_size >= need) {
    // fused path: xb | wt9 | qb | kb | vtb
    unsigned short* xb = (unsigned short*)d_ws;
    unsigned short* wt9 = xb + slab;
    unsigned short* qb = wt9 + wt9elems;
    unsigned short* kb = qb + slab;
    unsigned short* vtb = kb + slab;

    k_cvt_x<<<3072, 256, 0, stream>>>(x, xb);
    k_transpose3<<<dim3(DIM / 64, DIM / 64, 3), 256, 0, stream>>>(Wq, Wk, Wv, wt9);
    k_gemm3<<<1152, 256, 0, stream>>>(xb, wt9, bq, bk, bv, qb, kb, vtb);
    k_normrope2<<<2 * SEQ * NHEAD / 4, 256, 0, stream>>>(qb, kb, rope_cos, rope_sin, gq, gk);
    k_attn<<<768, 128, 0, stream>>>(qb, kb, vtb, out);
  } else {
    // sequential fallback (round-5 behavior)
    unsigned short* xb = (unsigned short*)d_ws;
    unsigned short* wt = xb + slab;
    unsigned short* qb = wt + (size_t)DIM * DIM;
    unsigned short* kb = qb + slab;
    unsigned short* vtb = kb + slab;

    k_cvt_x<<<3072, 256, 0, stream>>>(x, xb);
    dim3 tg(DIM / 64, DIM / 64);
    k_transpose<<<tg, 256, 0, stream>>>(Wq, wt);
    k_gemm<<<384, 256, 0, stream>>>(xb, wt, bq, qb, 0);
    k_transpose<<<tg, 256, 0, stream>>>(Wk, wt);
    k_gemm<<<384, 256, 0, stream>>>(xb, wt, bk, kb, 0);
    k_transpose<<<tg, 256, 0, stream>>>(Wv, wt);
    k_gemm<<<384, 256, 0, stream>>>(xb, wt, bv, vtb, 1);
    k_normrope<<<SEQ * NHEAD / 4, 256, 0, stream>>>(qb, rope_cos, rope_sin, gq, 0.12751744f);
    k_normrope<<<SEQ * NHEAD / 4, 256, 0, stream>>>(kb, rope_cos, rope_sin, gk, 1.0f);
    k_attn<<<768, 128, 0, stream>>>(qb, kb, vtb, out);
  }
}

// Round 7
// 286.801 us; speedup vs baseline: 1.3577x; 1.1083x over previous
//
#include <hip/hip_runtime.h>
#include <hip/hip_bf16.h>

typedef __attribute__((ext_vector_type(8))) short short8;
typedef __attribute__((ext_vector_type(4))) float f32x4;
typedef __attribute__((ext_vector_type(16))) float f32x16;

#define SEQ 2048
#define DIM 3072
#define NHEAD 24
#define HDIM 128
#define SCALE_Q 0.12751744f  // (1/sqrt(128)) * log2(e)

__device__ __forceinline__ unsigned short f2bf(float f) {
  unsigned int b = __float_as_uint(f);
  b += 0x7fffu + ((b >> 16) & 1u);
  return (unsigned short)(b >> 16);
}
__device__ __forceinline__ float bf2f(unsigned short u) {
  return __uint_as_float(((unsigned int)u) << 16);
}
__device__ __forceinline__ unsigned int pkbf(float a, float b) {
  __hip_bfloat162 h = __float22bfloat162_rn(make_float2(a, b));
  return *(unsigned int*)&h;
}

__device__ __forceinline__ void async16(const void* g, void* l) {
  __builtin_amdgcn_global_load_lds(
      (const __attribute__((address_space(1))) unsigned int*)g,
      (__attribute__((address_space(3))) unsigned int*)l, 16, 0, 0);
}

// ---------------- cast x (fp32 -> bf16), 8 elems/thread ----------------
__global__ void k_cvt_x(const float* __restrict__ x, unsigned short* __restrict__ xb) {
  int idx = (blockIdx.x * 256 + threadIdx.x) * 8;
  float4 a = *(const float4*)(x + idx);
  float4 b = *(const float4*)(x + idx + 4);
  short8 o;
  o[0] = (short)f2bf(a.x); o[1] = (short)f2bf(a.y);
  o[2] = (short)f2bf(a.z); o[3] = (short)f2bf(a.w);
  o[4] = (short)f2bf(b.x); o[5] = (short)f2bf(b.y);
  o[6] = (short)f2bf(b.z); o[7] = (short)f2bf(b.w);
  *(short8*)(xb + idx) = o;
}

// ---------------- transpose + cast one W (K x N fp32) -> Wt rows (N x K bf16) ----------------
__device__ __forceinline__ void transpose_tile(const float* __restrict__ w,
                                               unsigned short* __restrict__ wt,
                                               int n0, int k0, int outRowBase, int t) {
  __shared__ unsigned short tile[64][68];
  int c4 = (t & 15) * 4;
  int r0 = t >> 4;
#pragma unroll
  for (int j = 0; j < 4; ++j) {
    int r = r0 + 16 * j;
    float4 v = *(const float4*)(w + (size_t)(k0 + r) * DIM + n0 + c4);
    ushort4 u;
    u.x = f2bf(v.x); u.y = f2bf(v.y); u.z = f2bf(v.z); u.w = f2bf(v.w);
    *(ushort4*)&tile[r][c4] = u;
  }
  __syncthreads();
#pragma unroll
  for (int j = 0; j < 4; ++j) {
    int nn = r0 + 16 * j;
    ushort4 u;
    u.x = tile[c4 + 0][nn]; u.y = tile[c4 + 1][nn];
    u.z = tile[c4 + 2][nn]; u.w = tile[c4 + 3][nn];
    *(ushort4*)(wt + (size_t)(outRowBase + n0 + nn) * DIM + k0 + c4) = u;
  }
}

__global__ __launch_bounds__(256) void k_transpose(const float* __restrict__ w,
                                                   unsigned short* __restrict__ wt) {
  transpose_tile(w, wt, blockIdx.x * 64, blockIdx.y * 64, 0, threadIdx.x);
}

__global__ __launch_bounds__(256) void k_transpose3(const float* __restrict__ w0,
                                                    const float* __restrict__ w1,
                                                    const float* __restrict__ w2,
                                                    unsigned short* __restrict__ wt) {
  const float* w = blockIdx.z == 0 ? w0 : (blockIdx.z == 1 ? w1 : w2);
  transpose_tile(w, wt, blockIdx.x * 64, blockIdx.y * 64, blockIdx.z * DIM, threadIdx.x);
}

// ---------------- GEMM core: one 128x128 tile, BK=64, T2 swizzle ----------------
__device__ __forceinline__ void gemm_tile(const unsigned short* __restrict__ xb,
                                          const unsigned short* __restrict__ wt,
                                          int bm, int bn, int t, f32x4 (&acc)[4][4],
                                          unsigned short* As, unsigned short* Bs) {
  int l = t & 63, w = t >> 6;
  int wr = w >> 1, wc = w & 1;
  int lr = l & 15, kc = l >> 4;
  const char* aB = (const char*)xb;
  const char* bB = (const char*)wt;
  char* asmB = (char*)As;
  char* bsmB = (char*)Bs;
  int sw = (lr & 7) << 4;

  for (int k0 = 0; k0 < DIM; k0 += 64) {
#pragma unroll
    for (int i = 0; i < 4; ++i) {
      int off = (t + 256 * i) * 16;
      int row = off >> 7;
      int cb = off & 127;
      int scb = cb ^ ((row & 7) << 4);
      async16(aB + ((size_t)(bm * 128 + row) * DIM + k0) * 2 + scb, asmB + off);
      async16(bB + ((size_t)(bn * 128 + row) * DIM + k0) * 2 + scb, bsmB + off);
    }
    __syncthreads();
#pragma unroll
    for (int kk = 0; kk < 2; ++kk) {
      short8 af[4], bf[4];
#pragma unroll
      for (int m = 0; m < 4; ++m)
        af[m] = *(const short8*)(asmB + (wr * 64 + m * 16 + lr) * 128 +
                                 ((kk * 64 + kc * 16) ^ sw));
#pragma unroll
      for (int n = 0; n < 4; ++n)
        bf[n] = *(const short8*)(bsmB + (wc * 64 + n * 16 + lr) * 128 +
                                 ((kk * 64 + kc * 16) ^ sw));
#pragma unroll
      for (int m = 0; m < 4; ++m)
#pragma unroll
        for (int n = 0; n < 4; ++n)
          acc[m][n] = __builtin_amdgcn_mfma_f32_16x16x32_bf16(af[m], bf[n], acc[m][n], 0, 0, 0);
    }
    __syncthreads();
  }
}

// ---------------- fallback GEMM (one W at a time) ----------------
__global__ __launch_bounds__(256) void k_gemm(const unsigned short* __restrict__ xb,
                                              const unsigned short* __restrict__ wt,
                                              const float* __restrict__ bias,
                                              unsigned short* __restrict__ out,
                                              int vmode) {
  __shared__ unsigned short As[128 * 64];
  __shared__ unsigned short Bs[128 * 64];
  int t = threadIdx.x;
  int fid = blockIdx.x;
  int logical = (fid & 7) * 48 + (fid >> 3);
  int bm = logical & 15, bn = logical >> 4;

  f32x4 acc[4][4];
#pragma unroll
  for (int m = 0; m < 4; ++m)
#pragma unroll
    for (int n = 0; n < 4; ++n) acc[m][n] = (f32x4){0.f, 0.f, 0.f, 0.f};

  gemm_tile(xb, wt, bm, bn, t, acc, As, Bs);

  int l = t & 63, w = t >> 6;
  int wr = w >> 1, wc = w & 1;
  int lr = l & 15, lq = l >> 4;
  if (vmode) {
#pragma unroll
    for (int m = 0; m < 4; ++m)
#pragma unroll
      for (int n = 0; n < 4; ++n) {
        int gcol = bn * 128 + wc * 64 + n * 16 + lr;
        float bv = bias[gcol];
        int grow = bm * 128 + wr * 64 + m * 16 + lq * 4;
        ushort4 u;
        u.x = f2bf(acc[m][n][0] + bv);
        u.y = f2bf(acc[m][n][1] + bv);
        u.z = f2bf(acc[m][n][2] + bv);
        u.w = f2bf(acc[m][n][3] + bv);
        *(ushort4*)(out + (size_t)gcol * SEQ + grow) = u;
      }
  } else {
#pragma unroll
    for (int m = 0; m < 4; ++m)
#pragma unroll
      for (int n = 0; n < 4; ++n) {
        int gcol = bn * 128 + wc * 64 + n * 16 + lr;
        float bv = bias[gcol];
#pragma unroll
        for (int i = 0; i < 4; ++i) {
          int grow = bm * 128 + wr * 64 + m * 16 + lq * 4 + i;
          out[(size_t)grow * DIM + gcol] = f2bf(acc[m][n][i] + bv);
        }
      }
  }
}

// ---------------- fused GEMM + RMSNorm + RoPE epilogue ----------------
// C(2048 x 9216) = xb @ [Wq|Wk|Wv]^T. bn tile width 128 == one head, so the q/k
// epilogue has the full head-row in-block: row sum-of-squares via 4x shfl_xor +
// ssum[2][128] LDS exchange across the wc wave pair; RoPE pair via shfl_xor(1).
// 2D-chunked XCD traversal: 4-bm chunk stays L2-resident across the 9-bn sweep.
__global__ __launch_bounds__(256, 4) void k_gemm3(
    const unsigned short* __restrict__ xb, const unsigned short* __restrict__ wt,
    const float* __restrict__ bq, const float* __restrict__ bk,
    const float* __restrict__ bv, const float* __restrict__ rope_cos,
    const float* __restrict__ rope_sin, const float* __restrict__ gq,
    const float* __restrict__ gk, unsigned short* __restrict__ qb,
    unsigned short* __restrict__ kb, unsigned short* __restrict__ vtb) {
  __shared__ unsigned short As[128 * 64];
  __shared__ unsigned short Bs[128 * 64];
  __shared__ float ssum[2][128];
  int t = threadIdx.x;
  int fid = blockIdx.x;
  // bijective 1152 = 8 xcd * (4 chunks * 9 bn * 4 bmi)
  int xcd = fid & 7, li = fid >> 3;
  int c = li / 36, r = li % 36;
  int bnl9 = r >> 2, bmi = r & 3;
  int bm = c * 4 + bmi;        // 0..15
  int bn = xcd * 9 + bnl9;     // 0..71

  f32x4 acc[4][4];
#pragma unroll
  for (int m = 0; m < 4; ++m)
#pragma unroll
    for (int n = 0; n < 4; ++n) acc[m][n] = (f32x4){0.f, 0.f, 0.f, 0.f};

  gemm_tile(xb, wt, bm, bn, t, acc, As, Bs);

  int l = t & 63, w = t >> 6;
  int wr = w >> 1, wc = w & 1;
  int lr = l & 15, lq = l >> 4;

  int region = bn >= 48 ? 2 : (bn >= 24 ? 1 : 0);
  int bnl = bn - region * 24;  // head index for q/k; v col-block for region 2
  const float* bias = region == 0 ? bq : (region == 1 ? bk : bv);

  if (region == 2) {  // V: transposed write into vtb[d_global][s]
#pragma unroll
    for (int m = 0; m < 4; ++m)
#pragma unroll
      for (int n = 0; n < 4; ++n) {
        int gcol = bnl * 128 + wc * 64 + n * 16 + lr;
        float bv_ = bias[gcol];
        int grow = bm * 128 + wr * 64 + m * 16 + lq * 4;
        ushort4 u;
        u.x = f2bf(acc[m][n][0] + bv_);
        u.y = f2bf(acc[m][n][1] + bv_);
        u.z = f2bf(acc[m][n][2] + bv_);
        u.w = f2bf(acc[m][n][3] + bv_);
        *(ushort4*)(vtb + (size_t)gcol * SEQ + grow) = u;
      }
  } else {  // q/k: fused bias + RMSNorm + RoPE
    unsigned short* outp = region == 0 ? qb : kb;
    const float* g = region == 0 ? gq : gk;
    float scale = region == 0 ? SCALE_Q : 1.0f;

    float gv[4], bvv[4];
#pragma unroll
    for (int n = 0; n < 4; ++n) {
      int cl = wc * 64 + n * 16 + lr;
      gv[n] = g[cl];
      bvv[n] = bias[bnl * 128 + cl];
    }
#pragma unroll
    for (int m = 0; m < 4; ++m)
#pragma unroll
      for (int n = 0; n < 4; ++n)
#pragma unroll
        for (int i = 0; i < 4; ++i) acc[m][n][i] += bvv[n];

    // per-row sum of squares: reduce over 16 lanes (4 cols each x 4 n)
#pragma unroll
    for (int m = 0; m < 4; ++m)
#pragma unroll
      for (int i = 0; i < 4; ++i) {
        float ss = acc[m][0][i] * acc[m][0][i] + acc[m][1][i] * acc[m][1][i] +
                   acc[m][2][i] * acc[m][2][i] + acc[m][3][i] * acc[m][3][i];
        ss += __shfl_xor(ss, 1);
        ss += __shfl_xor(ss, 2);
        ss += __shfl_xor(ss, 4);
        ss += __shfl_xor(ss, 8);
        if (lr == m * 4 + i) ssum[wc][wr * 64 + m * 16 + lq * 4 + i] = ss;
      }
    __syncthreads();

#pragma unroll
    for (int m = 0; m < 4; ++m)
#pragma unroll
      for (int i = 0; i < 4; ++i) {
        int rl = wr * 64 + m * 16 + lq * 4 + i;
        float rn = rsqrtf((ssum[0][rl] + ssum[1][rl]) * (1.0f / 128.0f) + 1e-6f);
        int s_idx = bm * 128 + rl;
        const float* cr = rope_cos + (size_t)s_idx * HDIM;
        const float* sr = rope_sin + (size_t)s_idx * HDIM;
        unsigned short* orow = outp + (size_t)s_idx * DIM + bnl * 128;
#pragma unroll
        for (int n = 0; n < 4; ++n) {
          int cl = wc * 64 + n * 16 + lr;
          float xn = acc[m][n][i] * rn * gv[n];
          float pr = __shfl_xor(xn, 1);
          float cv = cr[cl], sv = sr[cl];
          float o = (lr & 1) ? fmaf(xn, cv, pr * sv) : fmaf(xn, cv, -pr * sv);
          orow[cl] = f2bf(o * scale);
        }
      }
  }
}

// ---------------- RMSNorm + RoPE (fallback path only) ----------------
__global__ void k_normrope(unsigned short* __restrict__ qk, const float* __restrict__ cosb,
                           const float* __restrict__ sinb, const float* __restrict__ g,
                           float scale) {
  int t = threadIdx.x;
  int w = t >> 6, l = t & 63;
  int row = blockIdx.x * 4 + w;
  int s_idx = row / NHEAD, head = row % NHEAD;
  size_t base = (size_t)s_idx * DIM + head * HDIM;
  unsigned int pair = *(const unsigned int*)(qk + base + 2 * l);
  float x0 = bf2f((unsigned short)(pair & 0xffffu));
  float x1 = bf2f((unsigned short)(pair >> 16));
  float ss = x0 * x0 + x1 * x1;
#pragma unroll
  for (int off = 1; off < 64; off <<= 1) ss += __shfl_xor(ss, off);
  float r = rsqrtf(ss * (1.0f / 128.0f) + 1e-6f);
  float g0 = g[2 * l], g1 = g[2 * l + 1];
  float c0 = cosb[s_idx * HDIM + 2 * l], c1 = cosb[s_idx * HDIM + 2 * l + 1];
  float s0 = sinb[s_idx * HDIM + 2 * l], s1 = sinb[s_idx * HDIM + 2 * l + 1];
  float xn0 = x0 * r * g0, xn1 = x1 * r * g1;
  float o0 = (xn0 * c0 - xn1 * s0) * scale;
  float o1 = (xn1 * c1 + xn0 * s1) * scale;
  unsigned int po = (unsigned int)f2bf(o0) | ((unsigned int)f2bf(o1) << 16);
  *(unsigned int*)(qk + base + 2 * l) = po;
}

// ---------------- Flash attention: swapped-QK^T 32x32, in-register softmax ----------------
__global__ __launch_bounds__(128, 2) void k_attn(const unsigned short* __restrict__ q,
                                                 const unsigned short* __restrict__ k,
                                                 const unsigned short* __restrict__ vt,
                                                 float* __restrict__ out) {
  __shared__ unsigned short Ksm[64 * 128];   // [kv][d], 4-bit swizzle
  __shared__ unsigned short Vtsm[128 * 64];  // [d][kv], 3-bit swizzle
  int t = threadIdx.x;       // 0..127
  int w = t >> 6, l = t & 63;
  int q32 = l & 31, hi = l >> 5;
  int hi4 = hi * 4;
  int fid = blockIdx.x;
  int logical = (fid & 7) * 96 + (fid >> 3);  // bijective: 768 = 8*96
  int qt = logical & 31, h = logical >> 5;
  int q0w = qt * 64 + w * 32;

  const char* kbase = (const char*)k + (size_t)h * HDIM * 2;
  const char* vbase = (const char*)vt + (size_t)h * HDIM * SEQ * 2;

  int koff[8], voff[8];
#pragma unroll
  for (int i = 0; i < 8; ++i) {
    int off = (t + 128 * i) * 16;
    int krow = off >> 8, kcb = off & 255;
    koff[i] = krow * (DIM * 2) + (kcb ^ ((krow & 15) << 4));
    int vrow = off >> 7, vcb = off & 127;
    voff[i] = vrow * (SEQ * 2) + (vcb ^ ((vrow & 7) << 4));
  }

  short8 qf[8];
  {
    const unsigned short* qrow = q + (size_t)(q0w + q32) * DIM + h * HDIM;
#pragma unroll
    for (int ks = 0; ks < 8; ++ks) qf[ks] = *(const short8*)(qrow + ks * 16 + hi * 8);
  }

  f32x16 o0 = {0.f,0.f,0.f,0.f,0.f,0.f,0.f,0.f,0.f,0.f,0.f,0.f,0.f,0.f,0.f,0.f};
  f32x16 o1 = o0, o2 = o0, o3 = o0;
  float m_ = -1e30f, lsum = 0.f;
  int ksw = (q32 & 15) << 4;
  int vsw = (q32 & 7) << 4;

  union U8 { short8 s8; unsigned int u[4]; };

  for (int kt = 0; kt < 32; ++kt) {
    const char* kt_k = kbase + (size_t)kt * (64 * DIM * 2);
    const char* kt_v = vbase + kt * 128;
#pragma unroll
    for (int i = 0; i < 8; ++i) {
      int dst = (t + 128 * i) * 16;
      async16(kt_k + koff[i], (char*)Ksm + dst);
      async16(kt_v + voff[i], (char*)Vtsm + dst);
    }
    __syncthreads();

    f32x16 st0 = {0.f,0.f,0.f,0.f,0.f,0.f,0.f,0.f,0.f,0.f,0.f,0.f,0.f,0.f,0.f,0.f};
    f32x16 st1 = st0;
    {
      const char* kr0 = (const char*)Ksm + q32 * 256;
      const char* kr1 = (const char*)Ksm + (32 + q32) * 256;
      __builtin_amdgcn_s_setprio(1);
#pragma unroll
      for (int ks = 0; ks < 8; ++ks) {
        int cb = (ks * 32 + hi * 16) ^ ksw;
        short8 kf0 = *(const short8*)(kr0 + cb);
        short8 kf1 = *(const short8*)(kr1 + cb);
        st0 = __builtin_amdgcn_mfma_f32_32x32x16_bf16(kf0, qf[ks], st0, 0, 0, 0);
        st1 = __builtin_amdgcn_mfma_f32_32x32x16_bf16(kf1, qf[ks], st1, 0, 0, 0);
      }
      __builtin_amdgcn_s_setprio(0);
    }

    float mx = fmaxf(st0[0], st1[0]);
#pragma unroll
    for (int r = 1; r < 16; ++r) mx = fmaxf(mx, fmaxf(st0[r], st1[r]));
    mx = fmaxf(mx, __shfl_xor(mx, 32));

    if (__any(mx > m_ + 10.0f)) {
      float mn = fmaxf(m_, mx);
      float corr = exp2f(m_ - mn);
      m_ = mn;
      lsum *= corr;
#pragma unroll
      for (int r = 0; r < 16; ++r) {
        float cr = __shfl(corr, (r & 3) + 8 * (r >> 2) + hi4);
        o0[r] *= cr; o1[r] *= cr; o2[r] *= cr; o3[r] *= cr;
      }
    }

#pragma unroll
    for (int r = 0; r < 16; ++r) {
      st0[r] = exp2f(st0[r] - m_);
      st1[r] = exp2f(st1[r] - m_);
    }
    {
      float sm = st0[0] + st1[0];
#pragma unroll
      for (int r = 1; r < 16; ++r) sm += st0[r] + st1[r];
      sm += __shfl_xor(sm, 32);
      lsum += sm;
    }

    U8 pa[4];
#pragma unroll
    for (int b = 0; b < 4; ++b) {
      unsigned int a0, a1, a2, a3;
      if (b < 2) {
        int r0 = (b & 1) * 8;
        a0 = pkbf(st0[r0 + 0], st0[r0 + 1]);
        a1 = pkbf(st0[r0 + 2], st0[r0 + 3]);
        a2 = pkbf(st0[r0 + 4], st0[r0 + 5]);
        a3 = pkbf(st0[r0 + 6], st0[r0 + 7]);
      } else {
        int r0 = (b & 1) * 8;
        a0 = pkbf(st1[r0 + 0], st1[r0 + 1]);
        a1 = pkbf(st1[r0 + 2], st1[r0 + 3]);
        a2 = pkbf(st1[r0 + 4], st1[r0 + 5]);
        a3 = pkbf(st1[r0 + 6], st1[r0 + 7]);
      }
      asm volatile("v_permlane32_swap_b32 %0, %1" : "+v"(a0), "+v"(a2));
      asm volatile("v_permlane32_swap_b32 %0, %1" : "+v"(a1), "+v"(a3));
      pa[b].u[0] = a0; pa[b].u[1] = a1; pa[b].u[2] = a2; pa[b].u[3] = a3;
    }

    __builtin_amdgcn_s_setprio(1);
#pragma unroll
    for (int ks = 0; ks < 4; ++ks) {
      int cb = (ks * 32 + hi * 16) ^ vsw;
      short8 vf0 = *(const short8*)((const char*)Vtsm + (0 * 32 + q32) * 128 + cb);
      short8 vf1 = *(const short8*)((const char*)Vtsm + (1 * 32 + q32) * 128 + cb);
      short8 vf2 = *(const short8*)((const char*)Vtsm + (2 * 32 + q32) * 128 + cb);
      short8 vf3 = *(const short8*)((const char*)Vtsm + (3 * 32 + q32) * 128 + cb);
      o0 = __builtin_amdgcn_mfma_f32_32x32x16_bf16(pa[ks].s8, vf0, o0, 0, 0, 0);
      o1 = __builtin_amdgcn_mfma_f32_32x32x16_bf16(pa[ks].s8, vf1, o1, 0, 0, 0);
      o2 = __builtin_amdgcn_mfma_f32_32x32x16_bf16(pa[ks].s8, vf2, o2, 0, 0, 0);
      o3 = __builtin_amdgcn_mfma_f32_32x32x16_bf16(pa[ks].s8, vf3, o3, 0, 0, 0);
    }
    __builtin_amdgcn_s_setprio(0);

    __syncthreads();
  }

  float inv = 1.0f / lsum;
#pragma unroll
  for (int r = 0; r < 16; ++r) {
    float fr = __shfl(inv, (r & 3) + 8 * (r >> 2) + hi4);
    int grow = q0w + (r & 3) + 8 * (r >> 2) + hi4;
    float* orow = out + (size_t)grow * DIM + h * HDIM + q32;
    orow[0]  = o0[r] * fr;
    orow[32] = o1[r] * fr;
    orow[64] = o2[r] * fr;
    orow[96] = o3[r] * fr;
  }
}

extern "C" void kernel_launch(void* const* d_in, const int* in_sizes, int n_in,
                              void* d_out, int out_size, void* d_ws, size_t ws_size,
                              hipStream_t stream) {
  const float* x = (const float*)d_in[0];
  const float* rope_cos = (const float*)d_in[1];
  const float* rope_sin = (const float*)d_in[2];
  const float* Wq = (const float*)d_in[3];
  const float* bq = (const float*)d_in[4];
  const float* Wk = (const float*)d_in[5];
  const float* bk = (const float*)d_in[6];
  const float* Wv = (const float*)d_in[7];
  const float* bv = (const float*)d_in[8];
  const float* gq = (const float*)d_in[9];
  const float* gk = (const float*)d_in[10];
  float* out = (float*)d_out;

  const size_t slab = (size_t)SEQ * DIM;          // bf16 elements
  const size_t wt9elems = (size_t)3 * DIM * DIM;  // fused W^T
  const size_t need = (4 * slab + wt9elems) * 2;  // bytes

  if (ws_size >= need) {
    // fused path: xb | wt9 | qb | kb | vtb
    unsigned short* xb = (unsigned short*)d_ws;
    unsigned short* wt9 = xb + slab;
    unsigned short* qb = wt9 + wt9elems;
    unsigned short* kb = qb + slab;
    unsigned short* vtb = kb + slab;

    k_cvt_x<<<3072, 256, 0, stream>>>(x, xb);
    k_transpose3<<<dim3(DIM / 64, DIM / 64, 3), 256, 0, stream>>>(Wq, Wk, Wv, wt9);
    k_gemm3<<<1152, 256, 0, stream>>>(xb, wt9, bq, bk, bv, rope_cos, rope_sin, gq, gk,
                                      qb, kb, vtb);
    k_attn<<<768, 128, 0, stream>>>(qb, kb, vtb, out);
  } else {
    // sequential fallback
    unsigned short* xb = (unsigned short*)d_ws;
    unsigned short* wt = xb + slab;
    unsigned short* qb = wt + (size_t)DIM * DIM;
    unsigned short* kb = qb + slab;
    unsigned short* vtb = kb + slab;

    k_cvt_x<<<3072, 256, 0, stream>>>(x, xb);
    dim3 tg(DIM / 64, DIM / 64);
    k_transpose<<<tg, 256, 0, stream>>>(Wq, wt);
    k_gemm<<<384, 256, 0, stream>>>(xb, wt, bq, qb, 0);
    k_transpose<<<tg, 256, 0, stream>>>(Wk, wt);
    k_gemm<<<384, 256, 0, stream>>>(xb, wt, bk, kb, 0);
    k_transpose<<<tg, 256, 0, stream>>>(Wv, wt);
    k_gemm<<<384, 256, 0, stream>>>(xb, wt, bv, vtb, 1);
    k_normrope<<<SEQ * NHEAD / 4, 256, 0, stream>>>(qb, rope_cos, rope_sin, gq, SCALE_Q);
    k_normrope<<<SEQ * NHEAD / 4, 256, 0, stream>>>(kb, rope_cos, rope_sin, gk, 1.0f);
    k_attn<<<768, 128, 0, stream>>>(qb, kb, vtb, out);
  }
}